// Round 9
// baseline (511.728 us; speedup 1.0000x reference)
//
#include <hip/hip_runtime.h>
#include <hip/hip_bf16.h>

typedef __attribute__((ext_vector_type(8))) short s16x8;
typedef __attribute__((ext_vector_type(8))) ushort u16x8;
typedef __attribute__((ext_vector_type(4))) float f32x4;

static __device__ __forceinline__ float b2f(ushort u) {
  union { float f; unsigned bits; } v; v.bits = ((unsigned)u) << 16; return v.f;
}
static __device__ __forceinline__ ushort f2b(float f) {
  __hip_bfloat16 h = __float2bfloat16(f);
  return *reinterpret_cast<ushort*>(&h);
}

// ---------------- dtype detector ----------------
// flag: 1 = inputs are f32, 0 = inputs are bf16.
__global__ void detect_dtype(const ushort* __restrict__ xraw, int* __restrict__ flag) {
  __shared__ int cnt;
  if (threadIdx.x == 0) cnt = 0;
  __syncthreads();
  ushort u = xraw[threadIdx.x];
  int e = (u >> 7) & 0xFF;
  if (e >= 113 && e <= 141) atomicAdd(&cnt, 1);
  __syncthreads();
  if (threadIdx.x == 0) *flag = (cnt >= 224) ? 0 : 1;
}

// ---------------- input conversion (dual path, 8 elems/thread) ----------------
__global__ void convert_x(const void* __restrict__ xin, ushort* __restrict__ xb,
                          const int* __restrict__ flag, int n) {
  int i = blockIdx.x * 256 + threadIdx.x;   // handles 8 elements
  int base = i * 8;
  if (base >= n) return;
  if (*flag) {
    const float4 v0 = ((const float4*)xin)[i * 2];
    const float4 v1 = ((const float4*)xin)[i * 2 + 1];
    u16x8 o;
    o[0] = f2b(v0.x); o[1] = f2b(v0.y); o[2] = f2b(v0.z); o[3] = f2b(v0.w);
    o[4] = f2b(v1.x); o[5] = f2b(v1.y); o[6] = f2b(v1.z); o[7] = f2b(v1.w);
    ((u16x8*)xb)[i] = o;
  } else {
    ((u16x8*)xb)[i] = ((const u16x8*)xin)[i];
  }
}

// ---------------- batched weight transpose+convert (7 matrices, 1 launch) ----------------
struct WDesc { const void* src; ushort* dst; int R, C; };
struct WPack { WDesc d[7]; };

__global__ void transpose_convert_all(WPack p, const int* __restrict__ flag) {
  const WDesc& d = p.d[blockIdx.y];
  int i = blockIdx.x * 256 + threadIdx.x;
  if (i >= d.R * d.C) return;
  int r = i / d.C, c = i % d.C;
  ushort v = (*flag) ? f2b(((const float*)d.src)[i]) : ((const ushort*)d.src)[i];
  d.dst[c * d.R + r] = v;
}

// ---------------- batched bias convert (5 vectors, 1 launch) ----------------
struct BPack { WDesc d[5]; };
__global__ void convert_vec_all(BPack p, const int* __restrict__ flag) {
  const WDesc& d = p.d[blockIdx.y];
  int i = threadIdx.x;
  if (i >= d.R) return;
  d.dst[i] = (*flag) ? f2b(((const float*)d.src)[i]) : ((const ushort*)d.src)[i];
}

// ---------------- CSR build (two-level counting sort) ----------------
// Bucket = dst >> 9 (512 nodes/bucket). NBUCK <= 512.

__global__ __launch_bounds__(256)
void hist_bucket_kernel(const int* __restrict__ dst, int* __restrict__ deg,
                        int* __restrict__ bcnt, int E, int N, int nbuck) {
  __shared__ int lh[512];
  int t = threadIdx.x;
  for (int i = t; i < nbuck; i += 256) lh[i] = 0;
  __syncthreads();
  int base = blockIdx.x * 2048;
#pragma unroll
  for (int k = 0; k < 8; ++k) {
    int e = base + k * 256 + t;
    if (e < E) {
      unsigned d = (unsigned)dst[e];
      if (d < (unsigned)N) {
        atomicAdd(&deg[d], 1);
        atomicAdd(&lh[d >> 9], 1);
      }
    }
  }
  __syncthreads();
  for (int i = t; i < nbuck; i += 256)
    if (lh[i]) atomicAdd(&bcnt[i], lh[i]);
}

__global__ __launch_bounds__(256)
void scan_buckets(const int* __restrict__ bcnt, int* __restrict__ bscan,
                  int* __restrict__ bpos, int nbuck) {
  int t = threadIdx.x;
  __shared__ int sh[256];
  int v = (t < nbuck) ? bcnt[t] : 0;
  sh[t] = v; __syncthreads();
  for (int off = 1; off < 256; off <<= 1) {
    int u = (t >= off) ? sh[t - off] : 0;
    __syncthreads();
    sh[t] += u;
    __syncthreads();
  }
  if (t < nbuck) { int ex = sh[t] - v; bscan[t] = ex; bpos[t] = ex; }
  if (t == nbuck - 1) bscan[nbuck] = sh[t];
}

__global__ __launch_bounds__(256)
void bin_scatter(const int* __restrict__ src, const int* __restrict__ dstl,
                 int* __restrict__ bpos, int2* __restrict__ pairs,
                 int E, int N, int nbuck) {
  __shared__ int lh[512];
  __shared__ int lbase[512];
  int t = threadIdx.x;
  for (int i = t; i < nbuck; i += 256) lh[i] = 0;
  __syncthreads();
  int base = blockIdx.x * 4096;
#pragma unroll
  for (int k = 0; k < 16; ++k) {
    int e = base + k * 256 + t;
    if (e < E) {
      unsigned d = (unsigned)dstl[e];
      if (d < (unsigned)N) atomicAdd(&lh[d >> 9], 1);
    }
  }
  __syncthreads();
  for (int i = t; i < nbuck; i += 256) {
    int c = lh[i];
    lbase[i] = c ? atomicAdd(&bpos[i], c) : 0;
    lh[i] = 0;
  }
  __syncthreads();
#pragma unroll
  for (int k = 0; k < 16; ++k) {
    int e = base + k * 256 + t;
    if (e < E) {
      unsigned d = (unsigned)dstl[e];
      if (d < (unsigned)N) {
        int b = d >> 9;
        int r = atomicAdd(&lh[b], 1);
        pairs[lbase[b] + r] = make_int2(src[e], (int)d);
      }
    }
  }
}

#define FS_SPLIT 4
__global__ __launch_bounds__(256)
void final_scatter(const int2* __restrict__ pairs, const int* __restrict__ bscan,
                   int* __restrict__ pos, int* __restrict__ eidx, int E) {
  int b = blockIdx.x / FS_SPLIT;
  int part = blockIdx.x % FS_SPLIT;
  int s = bscan[b], e = bscan[b + 1];
  int len = e - s;
  int per = (len + FS_SPLIT - 1) / FS_SPLIT;
  int lo = s + part * per;
  int hi = min(lo + per, e);
  for (int i = lo + threadIdx.x; i < hi; i += 256) {
    int2 p = pairs[i];
    unsigned q = (unsigned)atomicAdd(&pos[p.y], 1);
    if (q < (unsigned)E) eidx[q] = p.x;
  }
}

// 3-phase device-wide exclusive scan of deg -> rowptr/pos
__global__ __launch_bounds__(256)
void scan_phaseA(const int* __restrict__ deg, int* __restrict__ bsum, int N) {
  int b = blockIdx.x, t = threadIdx.x;
  int i0 = b * 1024 + t * 4;
  int s = 0;
#pragma unroll
  for (int k = 0; k < 4; ++k) {
    int i = i0 + k;
    if (i < N) s += deg[i];
  }
  __shared__ int red[256];
  red[t] = s; __syncthreads();
  for (int off = 128; off > 0; off >>= 1) {
    if (t < off) red[t] += red[t + off];
    __syncthreads();
  }
  if (t == 0) bsum[b] = red[0];
}

__global__ __launch_bounds__(256)
void scan_phaseB(const int* __restrict__ bsum, int* __restrict__ ebsum,
                 int* __restrict__ rowptr, int B, int N) {
  int t = threadIdx.x;
  __shared__ int sh[256];
  int v = (t < B) ? bsum[t] : 0;
  sh[t] = v; __syncthreads();
  for (int off = 1; off < 256; off <<= 1) {
    int u = (t >= off) ? sh[t - off] : 0;
    __syncthreads();
    sh[t] += u;
    __syncthreads();
  }
  if (t < B) ebsum[t] = sh[t] - v;
  if (t == B - 1) rowptr[N] = sh[t];
}

__global__ __launch_bounds__(256)
void scan_phaseC(const int* __restrict__ deg, const int* __restrict__ ebsum,
                 int* __restrict__ rowptr, int* __restrict__ pos, int N) {
  int b = blockIdx.x, t = threadIdx.x;
  int i0 = b * 1024 + t * 4;
  int v[4]; int s = 0;
#pragma unroll
  for (int k = 0; k < 4; ++k) {
    int i = i0 + k;
    v[k] = (i < N) ? deg[i] : 0;
    s += v[k];
  }
  __shared__ int sh[256];
  sh[t] = s; __syncthreads();
  for (int off = 1; off < 256; off <<= 1) {
    int u = (t >= off) ? sh[t - off] : 0;
    __syncthreads();
    sh[t] += u;
    __syncthreads();
  }
  int run = ebsum[b] + sh[t] - s;
#pragma unroll
  for (int k = 0; k < 4; ++k) {
    int i = i0 + k;
    if (i < N) { rowptr[i] = run; pos[i] = run; run += v[k]; }
  }
}

// ---------------- mean aggregation v3 (wave-per-node, 16B/lane, 2 rows/load) ----------------
// Proven config: 20 VGPR, ~73% occupancy, ~89 us/dispatch. (v4's 4-deep
// batching regressed: +12 VGPR, -5% occ, no latency win -> reverted.)
__global__ __launch_bounds__(256)
void agg_mean_v3(const ushort* __restrict__ xp, const int* __restrict__ rowptr,
                 const int* __restrict__ eidx, ushort* __restrict__ mean, int NN) {
  int node = blockIdx.x * 4 + (threadIdx.x >> 6);
  if (node >= NN) return;
  int lane = threadIdx.x & 63;
  int half = lane >> 5;        // 0 = even neighbor, 1 = odd neighbor
  int l32 = lane & 31;         // feature block: features l32*8 .. +7
  int s = rowptr[node], e = rowptr[node + 1];
  float a[8];
#pragma unroll
  for (int k = 0; k < 8; ++k) a[k] = 0.f;

  for (int base = s; base < e; base += 64) {
    int cnt = min(64, e - base);
    int my = (lane < cnt) ? eidx[base + lane] : 0;
    int full = cnt >> 1;
#pragma unroll 2
    for (int it = 0; it < full; ++it) {
      int sn = __shfl(my, 2 * it + half);
      u16x8 v = *(const u16x8*)&xp[(size_t)sn * 256 + l32 * 8];
#pragma unroll
      for (int k = 0; k < 8; ++k) a[k] += b2f(v[k]);
    }
    if (cnt & 1) {
      int sn = __shfl(my, cnt - 1);
      if (half == 0) {
        u16x8 v = *(const u16x8*)&xp[(size_t)sn * 256 + l32 * 8];
#pragma unroll
        for (int k = 0; k < 8; ++k) a[k] += b2f(v[k]);
      }
    }
  }
#pragma unroll
  for (int k = 0; k < 8; ++k) a[k] += __shfl_xor(a[k], 32);

  int c = e - s; if (c < 1) c = 1;
  float inv = 1.f / (float)c;
  if (half == 0) {
    u16x8 o;
#pragma unroll
    for (int k = 0; k < 8; ++k) o[k] = f2b(a[k] * inv);
    *(u16x8*)&mean[(size_t)node * 256 + l32 * 8] = o;
  }
}

// ---------------- MFMA GEMM: C = act(A1@B1^T + A2@B2^T + bias) ----------------
#define GLD16(g, l) \
  __builtin_amdgcn_global_load_lds((const __attribute__((address_space(1))) void*)(g), \
                                   (__attribute__((address_space(3))) void*)(l), 16, 0, 0)

// launch_bounds(256,3): 3 blocks/CU resident (16KB LDS each) so other blocks'
// MFMA hides this block's vmcnt(0)+barrier drain (m114 overlap mechanism).
__global__ __launch_bounds__(256, 3)
void gemm_bf16(const ushort* __restrict__ A1, const ushort* __restrict__ B1,
               const ushort* __restrict__ A2, const ushort* __restrict__ B2,
               const ushort* __restrict__ bias, ushort* __restrict__ C,
               float* __restrict__ Cf, const int* __restrict__ flag,
               int M, int N, int K1, int K2, int do_relu) {
  __shared__ __align__(16) ushort lsA[128 * 32];
  __shared__ __align__(16) ushort lsB[128 * 32];
  const int tid = threadIdx.x;
  const int lane = tid & 63;
  const int wid = tid >> 6;
  const int wr = wid >> 1, wc = wid & 1;
  const int m0 = blockIdx.x * 128;
  const int n0 = blockIdx.y * 128;
  const int l15 = lane & 15;
  const int lg = lane >> 4;
  const int fl = Cf ? *flag : 0;

  f32x4 acc[4][4];
#pragma unroll
  for (int i = 0; i < 4; ++i)
#pragma unroll
    for (int j = 0; j < 4; ++j) {
      acc[i][j][0] = 0.f; acc[i][j][1] = 0.f; acc[i][j][2] = 0.f; acc[i][j][3] = 0.f;
    }

#pragma unroll
  for (int pass = 0; pass < 2; ++pass) {
    const ushort* A = pass ? A2 : A1;
    const ushort* B = pass ? B2 : B1;
    const int K = pass ? K2 : K1;
    if (K == 0) continue;
    for (int k0 = 0; k0 < K; k0 += 32) {
#pragma unroll
      for (int it = 0; it < 2; ++it) {
        int o = tid * 16 + it * 4096;   // byte offset within 8KB tile
        int row = o >> 6;               // 64 bytes per row
        int colb = o & 63;
        const ushort* ga = A + (size_t)(m0 + row) * K + k0 + (colb >> 1);
        GLD16(ga, (char*)lsA + o);
        const ushort* gb = B + (size_t)(n0 + row) * K + k0 + (colb >> 1);
        GLD16(gb, (char*)lsB + o);
      }
      __syncthreads();
      s16x8 af[4], bfr[4];
#pragma unroll
      for (int i = 0; i < 4; ++i)
        af[i] = *(const s16x8*)&lsA[(wr * 64 + i * 16 + l15) * 32 + lg * 8];
#pragma unroll
      for (int j = 0; j < 4; ++j)
        bfr[j] = *(const s16x8*)&lsB[(wc * 64 + j * 16 + l15) * 32 + lg * 8];
#pragma unroll
      for (int i = 0; i < 4; ++i)
#pragma unroll
        for (int j = 0; j < 4; ++j)
          acc[i][j] = __builtin_amdgcn_mfma_f32_16x16x32_bf16(af[i], bfr[j], acc[i][j], 0, 0, 0);
      __syncthreads();
    }
  }

#pragma unroll
  for (int j = 0; j < 4; ++j) {
    int col = n0 + wc * 64 + j * 16 + l15;
    float bv = bias ? b2f(bias[col]) : 0.f;
#pragma unroll
    for (int i = 0; i < 4; ++i) {
      int rbase = m0 + wr * 64 + i * 16 + lg * 4;
#pragma unroll
      for (int r = 0; r < 4; ++r) {
        float v = acc[i][j][r] + bv;
        if (do_relu) v = fmaxf(v, 0.f);
        size_t idx = (size_t)(rbase + r) * N + col;
        if (Cf) {
          if (fl) Cf[idx] = v;
          else    C[idx] = f2b(v);
        } else {
          C[idx] = f2b(v);
        }
      }
    }
  }
}

// ---------------- kriging gather (reads dual-dtype h region of d_out) ----------------
__global__ void gather_out(const ushort* __restrict__ hb, const float* __restrict__ hf,
                           const int* __restrict__ map_id, void* __restrict__ dout,
                           const int* __restrict__ flag,
                           int K, int num_nodes, int total, int N) {
  int i = blockIdx.x * 256 + threadIdx.x;
  if (i >= total) return;
  int f = i & 127;
  int row = i >> 7;
  int b = row / K;
  unsigned node = (unsigned)(b * num_nodes + map_id[row]);
  bool ok = node < (unsigned)N;
  if (*flag) {
    ((float*)dout)[i] = ok ? hf[(size_t)node * 128 + f] : 0.f;
  } else {
    ((ushort*)dout)[i] = ok ? hb[(size_t)node * 128 + f] : (ushort)0;
  }
}

extern "C" void kernel_launch(void* const* d_in, const int* in_sizes, int n_in,
                              void* d_out, int out_size, void* d_ws, size_t ws_size,
                              hipStream_t stream) {
  const void* x    = d_in[0];
  const int*  ei   = (const int*)d_in[1];
  const int*  mapi = (const int*)d_in[2];
  const void* Wp1  = d_in[4];
  const void* bp1  = d_in[5];
  const void* Wl1  = d_in[6];
  const void* bl1  = d_in[7];
  const void* Wr1  = d_in[8];
  const void* Wp2  = d_in[9];
  const void* bp2  = d_in[10];
  const void* Wl2  = d_in[11];
  const void* bl2  = d_in[12];
  const void* Wr2  = d_in[13];
  const void* Wlin = d_in[14];
  const void* blin = d_in[15];

  const int NN = in_sizes[0] / 256;   // 80000
  const int E  = in_sizes[1] / 2;     // 1.28M
  const int MAPROWS = in_sizes[2];    // 40000
  const int BS = 16;
  const int NUM_NODES = NN / BS;      // 5000
  const int KMAP = MAPROWS / BS;      // 2500
  const int NBUCK = (NN + 511) >> 9;  // 157 buckets of 512 nodes
  const int* src = ei;
  const int* dst = ei + E;

  ushort* houtB = (ushort*)d_out + (size_t)MAPROWS * 128;
  float*  houtF = (float*)d_out + (size_t)MAPROWS * 128;

  int2* pairs = (int2*)((char*)d_out + (size_t)MAPROWS * 128 * 4);

  char* sc = (char*)d_out;
  auto carve_sc = [&](size_t bytes) {
    char* p = sc; sc += (bytes + 255) & ~(size_t)255; return p;
  };
  ushort* Wp1T  = (ushort*)carve_sc(256 * 256 * 2);
  ushort* Wl1T  = (ushort*)carve_sc(256 * 256 * 2);
  ushort* Wr1T  = (ushort*)carve_sc(256 * 256 * 2);
  ushort* Wp2T  = (ushort*)carve_sc(256 * 256 * 2);
  ushort* Wl2T  = (ushort*)carve_sc(128 * 256 * 2);
  ushort* Wr2T  = (ushort*)carve_sc(128 * 256 * 2);
  ushort* WlinT = (ushort*)carve_sc(128 * 128 * 2);
  ushort* bp1c  = (ushort*)carve_sc(256 * 2);
  ushort* bl1c  = (ushort*)carve_sc(256 * 2);
  ushort* bp2c  = (ushort*)carve_sc(256 * 2);
  ushort* bl2c  = (ushort*)carve_sc(128 * 2);
  ushort* blinc = (ushort*)carve_sc(128 * 2);
  int* deg    = (int*)carve_sc((size_t)NN * 4);
  int* rowptr = (int*)carve_sc(((size_t)NN + 1) * 4);
  int* pos    = (int*)carve_sc((size_t)NN * 4);
  int* eidx   = (int*)carve_sc((size_t)E * 4);
  int* bsum   = (int*)carve_sc(1024);
  int* ebsum  = (int*)carve_sc(1024);
  int* bcnt   = (int*)carve_sc(2048);
  int* bscan  = (int*)carve_sc(2048 + 4);
  int* bpos   = (int*)carve_sc(2048);

  char* w = (char*)d_ws;
  auto carve = [&](size_t bytes) {
    char* p = w; w += (bytes + 255) & ~(size_t)255; return p;
  };
  int*    flag = (int*)carve(256);
  ushort* xb   = (ushort*)carve((size_t)NN * 256 * 2);  // x_bf16 -> mean2
  ushort* bA   = (ushort*)carve((size_t)NN * 256 * 2);  // xp1 -> h1
  ushort* bB   = (ushort*)carve((size_t)NN * 256 * 2);  // mean1 -> xp2 -> h2

  // --- dtype detect + conversions ---
  detect_dtype<<<dim3(1), 256, 0, stream>>>((const ushort*)x, flag);
  convert_x<<<dim3((NN * 256 / 8 + 255) / 256), 256, 0, stream>>>(x, xb, flag, NN * 256);

  WPack wp;
  wp.d[0] = {Wp1, Wp1T, 256, 256};
  wp.d[1] = {Wl1, Wl1T, 256, 256};
  wp.d[2] = {Wr1, Wr1T, 256, 256};
  wp.d[3] = {Wp2, Wp2T, 256, 256};
  wp.d[4] = {Wl2, Wl2T, 256, 128};
  wp.d[5] = {Wr2, Wr2T, 256, 128};
  wp.d[6] = {Wlin, WlinT, 128, 128};
  transpose_convert_all<<<dim3(256, 7), 256, 0, stream>>>(wp, flag);

  BPack bp;
  bp.d[0] = {bp1, bp1c, 256, 1};
  bp.d[1] = {bl1, bl1c, 256, 1};
  bp.d[2] = {bp2, bp2c, 256, 1};
  bp.d[3] = {bl2, bl2c, 128, 1};
  bp.d[4] = {blin, blinc, 128, 1};
  convert_vec_all<<<dim3(1, 5), 256, 0, stream>>>(bp, flag);

  // --- CSR build (two-level counting sort) ---
  hipMemsetAsync(deg, 0, (size_t)NN * 4, stream);
  hipMemsetAsync(bcnt, 0, 2048, stream);
  hist_bucket_kernel<<<dim3((E + 2047) / 2048), 256, 0, stream>>>(dst, deg, bcnt, E, NN, NBUCK);
  scan_buckets<<<dim3(1), 256, 0, stream>>>(bcnt, bscan, bpos, NBUCK);
  int SB = (NN + 1023) / 1024;
  scan_phaseA<<<dim3(SB), 256, 0, stream>>>(deg, bsum, NN);
  scan_phaseB<<<dim3(1), 256, 0, stream>>>(bsum, ebsum, rowptr, SB, NN);
  scan_phaseC<<<dim3(SB), 256, 0, stream>>>(deg, ebsum, rowptr, pos, NN);
  bin_scatter<<<dim3((E + 4095) / 4096), 256, 0, stream>>>(src, dst, bpos, pairs, E, NN, NBUCK);
  final_scatter<<<dim3(NBUCK * FS_SPLIT), 256, 0, stream>>>(pairs, bscan, pos, eidx, E);

  dim3 blk(256);
  dim3 g256(NN / 128, 2);   // N=256
  dim3 g128(NN / 128, 1);   // N=128
  dim3 gagg((NN + 3) / 4);

  // --- layer 1 ---
  gemm_bf16<<<g256, blk, 0, stream>>>(xb, Wp1T, nullptr, nullptr, bp1c, bA,
                                      nullptr, nullptr, NN, 256, 256, 0, 1);        // xp1
  agg_mean_v3<<<gagg, blk, 0, stream>>>(bA, rowptr, eidx, bB, NN);                  // mean1
  gemm_bf16<<<g256, blk, 0, stream>>>(bB, Wl1T, xb, Wr1T, bl1c, bA,
                                      nullptr, nullptr, NN, 256, 256, 256, 1);      // h1

  // --- layer 2 ---
  gemm_bf16<<<g256, blk, 0, stream>>>(bA, Wp2T, nullptr, nullptr, bp2c, bB,
                                      nullptr, nullptr, NN, 256, 256, 0, 1);        // xp2
  agg_mean_v3<<<gagg, blk, 0, stream>>>(bB, rowptr, eidx, xb, NN);                  // mean2
  gemm_bf16<<<g128, blk, 0, stream>>>(xb, Wl2T, bA, Wr2T, bl2c, bB,
                                      nullptr, nullptr, NN, 128, 256, 256, 1);      // h2

  // --- final linear: write dual-dtype h straight into d_out h region ---
  gemm_bf16<<<g128, blk, 0, stream>>>(bB, WlinT, nullptr, nullptr, blinc, houtB,
                                      houtF, flag, NN, 128, 128, 0, 0);

  // --- kriging gather -> d_out local_feat region (overwrites scratch, last use) ---
  int total = MAPROWS * 128;
  gather_out<<<dim3((total + 255) / 256), 256, 0, stream>>>(houtB, houtF, mapi, d_out,
                                                            flag, KMAP, NUM_NODES, total, NN);
}

// Round 10
// 493.172 us; speedup vs baseline: 1.0376x; 1.0376x over previous
//
#include <hip/hip_runtime.h>
#include <hip/hip_bf16.h>

typedef __attribute__((ext_vector_type(8))) short s16x8;
typedef __attribute__((ext_vector_type(8))) ushort u16x8;
typedef __attribute__((ext_vector_type(4))) float f32x4;

static __device__ __forceinline__ float b2f(ushort u) {
  union { float f; unsigned bits; } v; v.bits = ((unsigned)u) << 16; return v.f;
}
static __device__ __forceinline__ ushort f2b(float f) {
  __hip_bfloat16 h = __float2bfloat16(f);
  return *reinterpret_cast<ushort*>(&h);
}

// ---------------- dtype detector ----------------
// flag: 1 = inputs are f32, 0 = inputs are bf16.
__global__ void detect_dtype(const ushort* __restrict__ xraw, int* __restrict__ flag) {
  __shared__ int cnt;
  if (threadIdx.x == 0) cnt = 0;
  __syncthreads();
  ushort u = xraw[threadIdx.x];
  int e = (u >> 7) & 0xFF;
  if (e >= 113 && e <= 141) atomicAdd(&cnt, 1);
  __syncthreads();
  if (threadIdx.x == 0) *flag = (cnt >= 224) ? 0 : 1;
}

// ---------------- input conversion (dual path, 8 elems/thread) ----------------
__global__ void convert_x(const void* __restrict__ xin, ushort* __restrict__ xb,
                          const int* __restrict__ flag, int n) {
  int i = blockIdx.x * 256 + threadIdx.x;   // handles 8 elements
  int base = i * 8;
  if (base >= n) return;
  if (*flag) {
    const float4 v0 = ((const float4*)xin)[i * 2];
    const float4 v1 = ((const float4*)xin)[i * 2 + 1];
    u16x8 o;
    o[0] = f2b(v0.x); o[1] = f2b(v0.y); o[2] = f2b(v0.z); o[3] = f2b(v0.w);
    o[4] = f2b(v1.x); o[5] = f2b(v1.y); o[6] = f2b(v1.z); o[7] = f2b(v1.w);
    ((u16x8*)xb)[i] = o;
  } else {
    ((u16x8*)xb)[i] = ((const u16x8*)xin)[i];
  }
}

// ---------------- batched weight transpose+convert (7 matrices, 1 launch) ----------------
struct WDesc { const void* src; ushort* dst; int R, C; };
struct WPack { WDesc d[7]; };

__global__ void transpose_convert_all(WPack p, const int* __restrict__ flag) {
  const WDesc& d = p.d[blockIdx.y];
  int i = blockIdx.x * 256 + threadIdx.x;
  if (i >= d.R * d.C) return;
  int r = i / d.C, c = i % d.C;
  ushort v = (*flag) ? f2b(((const float*)d.src)[i]) : ((const ushort*)d.src)[i];
  d.dst[c * d.R + r] = v;
}

// ---------------- batched bias convert (5 vectors, 1 launch) ----------------
struct BPack { WDesc d[5]; };
__global__ void convert_vec_all(BPack p, const int* __restrict__ flag) {
  const WDesc& d = p.d[blockIdx.y];
  int i = threadIdx.x;
  if (i >= d.R) return;
  d.dst[i] = (*flag) ? f2b(((const float*)d.src)[i]) : ((const ushort*)d.src)[i];
}

// ---------------- CSR build (two-level counting sort) ----------------
// Bucket = dst >> 9 (512 nodes/bucket). NBUCK <= 512.

__global__ __launch_bounds__(256)
void hist_bucket_kernel(const int* __restrict__ dst, int* __restrict__ deg,
                        int* __restrict__ bcnt, int E, int N, int nbuck) {
  __shared__ int lh[512];
  int t = threadIdx.x;
  for (int i = t; i < nbuck; i += 256) lh[i] = 0;
  __syncthreads();
  int base = blockIdx.x * 2048;
#pragma unroll
  for (int k = 0; k < 8; ++k) {
    int e = base + k * 256 + t;
    if (e < E) {
      unsigned d = (unsigned)dst[e];
      if (d < (unsigned)N) {
        atomicAdd(&deg[d], 1);
        atomicAdd(&lh[d >> 9], 1);
      }
    }
  }
  __syncthreads();
  for (int i = t; i < nbuck; i += 256)
    if (lh[i]) atomicAdd(&bcnt[i], lh[i]);
}

__global__ __launch_bounds__(256)
void scan_buckets(const int* __restrict__ bcnt, int* __restrict__ bscan,
                  int* __restrict__ bpos, int nbuck) {
  int t = threadIdx.x;
  __shared__ int sh[256];
  int v = (t < nbuck) ? bcnt[t] : 0;
  sh[t] = v; __syncthreads();
  for (int off = 1; off < 256; off <<= 1) {
    int u = (t >= off) ? sh[t - off] : 0;
    __syncthreads();
    sh[t] += u;
    __syncthreads();
  }
  if (t < nbuck) { int ex = sh[t] - v; bscan[t] = ex; bpos[t] = ex; }
  if (t == nbuck - 1) bscan[nbuck] = sh[t];
}

__global__ __launch_bounds__(256)
void bin_scatter(const int* __restrict__ src, const int* __restrict__ dstl,
                 int* __restrict__ bpos, int2* __restrict__ pairs,
                 int E, int N, int nbuck) {
  __shared__ int lh[512];
  __shared__ int lbase[512];
  int t = threadIdx.x;
  for (int i = t; i < nbuck; i += 256) lh[i] = 0;
  __syncthreads();
  int base = blockIdx.x * 4096;
#pragma unroll
  for (int k = 0; k < 16; ++k) {
    int e = base + k * 256 + t;
    if (e < E) {
      unsigned d = (unsigned)dstl[e];
      if (d < (unsigned)N) atomicAdd(&lh[d >> 9], 1);
    }
  }
  __syncthreads();
  for (int i = t; i < nbuck; i += 256) {
    int c = lh[i];
    lbase[i] = c ? atomicAdd(&bpos[i], c) : 0;
    lh[i] = 0;
  }
  __syncthreads();
#pragma unroll
  for (int k = 0; k < 16; ++k) {
    int e = base + k * 256 + t;
    if (e < E) {
      unsigned d = (unsigned)dstl[e];
      if (d < (unsigned)N) {
        int b = d >> 9;
        int r = atomicAdd(&lh[b], 1);
        pairs[lbase[b] + r] = make_int2(src[e], (int)d);
      }
    }
  }
}

#define FS_SPLIT 4
__global__ __launch_bounds__(256)
void final_scatter(const int2* __restrict__ pairs, const int* __restrict__ bscan,
                   int* __restrict__ pos, int* __restrict__ eidx, int E) {
  int b = blockIdx.x / FS_SPLIT;
  int part = blockIdx.x % FS_SPLIT;
  int s = bscan[b], e = bscan[b + 1];
  int len = e - s;
  int per = (len + FS_SPLIT - 1) / FS_SPLIT;
  int lo = s + part * per;
  int hi = min(lo + per, e);
  for (int i = lo + threadIdx.x; i < hi; i += 256) {
    int2 p = pairs[i];
    unsigned q = (unsigned)atomicAdd(&pos[p.y], 1);
    if (q < (unsigned)E) eidx[q] = p.x;
  }
}

// 3-phase device-wide exclusive scan of deg -> rowptr/pos
__global__ __launch_bounds__(256)
void scan_phaseA(const int* __restrict__ deg, int* __restrict__ bsum, int N) {
  int b = blockIdx.x, t = threadIdx.x;
  int i0 = b * 1024 + t * 4;
  int s = 0;
#pragma unroll
  for (int k = 0; k < 4; ++k) {
    int i = i0 + k;
    if (i < N) s += deg[i];
  }
  __shared__ int red[256];
  red[t] = s; __syncthreads();
  for (int off = 128; off > 0; off >>= 1) {
    if (t < off) red[t] += red[t + off];
    __syncthreads();
  }
  if (t == 0) bsum[b] = red[0];
}

__global__ __launch_bounds__(256)
void scan_phaseB(const int* __restrict__ bsum, int* __restrict__ ebsum,
                 int* __restrict__ rowptr, int B, int N) {
  int t = threadIdx.x;
  __shared__ int sh[256];
  int v = (t < B) ? bsum[t] : 0;
  sh[t] = v; __syncthreads();
  for (int off = 1; off < 256; off <<= 1) {
    int u = (t >= off) ? sh[t - off] : 0;
    __syncthreads();
    sh[t] += u;
    __syncthreads();
  }
  if (t < B) ebsum[t] = sh[t] - v;
  if (t == B - 1) rowptr[N] = sh[t];
}

__global__ __launch_bounds__(256)
void scan_phaseC(const int* __restrict__ deg, const int* __restrict__ ebsum,
                 int* __restrict__ rowptr, int* __restrict__ pos, int N) {
  int b = blockIdx.x, t = threadIdx.x;
  int i0 = b * 1024 + t * 4;
  int v[4]; int s = 0;
#pragma unroll
  for (int k = 0; k < 4; ++k) {
    int i = i0 + k;
    v[k] = (i < N) ? deg[i] : 0;
    s += v[k];
  }
  __shared__ int sh[256];
  sh[t] = s; __syncthreads();
  for (int off = 1; off < 256; off <<= 1) {
    int u = (t >= off) ? sh[t - off] : 0;
    __syncthreads();
    sh[t] += u;
    __syncthreads();
  }
  int run = ebsum[b] + sh[t] - s;
#pragma unroll
  for (int k = 0; k < 4; ++k) {
    int i = i0 + k;
    if (i < N) { rowptr[i] = run; pos[i] = run; run += v[k]; }
  }
}

// ---------------- mean aggregation v3 (wave-per-node, 16B/lane, 2 rows/load) ----------------
// Proven config: 20 VGPR, ~73% occupancy, ~89 us/dispatch.
__global__ __launch_bounds__(256)
void agg_mean_v3(const ushort* __restrict__ xp, const int* __restrict__ rowptr,
                 const int* __restrict__ eidx, ushort* __restrict__ mean, int NN) {
  int node = blockIdx.x * 4 + (threadIdx.x >> 6);
  if (node >= NN) return;
  int lane = threadIdx.x & 63;
  int half = lane >> 5;        // 0 = even neighbor, 1 = odd neighbor
  int l32 = lane & 31;         // feature block: features l32*8 .. +7
  int s = rowptr[node], e = rowptr[node + 1];
  float a[8];
#pragma unroll
  for (int k = 0; k < 8; ++k) a[k] = 0.f;

  for (int base = s; base < e; base += 64) {
    int cnt = min(64, e - base);
    int my = (lane < cnt) ? eidx[base + lane] : 0;
    int full = cnt >> 1;
#pragma unroll 2
    for (int it = 0; it < full; ++it) {
      int sn = __shfl(my, 2 * it + half);
      u16x8 v = *(const u16x8*)&xp[(size_t)sn * 256 + l32 * 8];
#pragma unroll
      for (int k = 0; k < 8; ++k) a[k] += b2f(v[k]);
    }
    if (cnt & 1) {
      int sn = __shfl(my, cnt - 1);
      if (half == 0) {
        u16x8 v = *(const u16x8*)&xp[(size_t)sn * 256 + l32 * 8];
#pragma unroll
        for (int k = 0; k < 8; ++k) a[k] += b2f(v[k]);
      }
    }
  }
#pragma unroll
  for (int k = 0; k < 8; ++k) a[k] += __shfl_xor(a[k], 32);

  int c = e - s; if (c < 1) c = 1;
  float inv = 1.f / (float)c;
  if (half == 0) {
    u16x8 o;
#pragma unroll
    for (int k = 0; k < 8; ++k) o[k] = f2b(a[k] * inv);
    *(u16x8*)&mean[(size_t)node * 256 + l32 * 8] = o;
  }
}

// ---------------- MFMA GEMM v2: BK=64, XOR-swizzled LDS ----------------
// C = act(A1@B1^T + A2@B2^T + bias). 128x128 tile, 4 waves 2x2.
// BK=64 halves barrier/drain count vs BK=32. LDS [128][64] ushort per matrix;
// st-swizzle byte_col ^= (row&7)<<4 applied on BOTH the global source column
// (inverse pre-swizzle, since global_load_lds writes linearly - m104/m231)
// and the ds_read address. Bank spread: 8 lanes per 4-bank group = optimal.
#define GLD16(g, l) \
  __builtin_amdgcn_global_load_lds((const __attribute__((address_space(1))) void*)(g), \
                                   (__attribute__((address_space(3))) void*)(l), 16, 0, 0)

__global__ __launch_bounds__(256, 3)
void gemm_bf16(const ushort* __restrict__ A1, const ushort* __restrict__ B1,
               const ushort* __restrict__ A2, const ushort* __restrict__ B2,
               const ushort* __restrict__ bias, ushort* __restrict__ C,
               float* __restrict__ Cf, const int* __restrict__ flag,
               int M, int N, int K1, int K2, int do_relu) {
  __shared__ __align__(16) ushort lsA[128 * 64];
  __shared__ __align__(16) ushort lsB[128 * 64];
  const int tid = threadIdx.x;
  const int lane = tid & 63;
  const int wid = tid >> 6;
  const int wr = wid >> 1, wc = wid & 1;
  const int m0 = blockIdx.x * 128;
  const int n0 = blockIdx.y * 128;
  const int l15 = lane & 15;
  const int lg = lane >> 4;
  const int fl = Cf ? *flag : 0;

  // staging geometry (4 chunks of 16B per thread per matrix)
  const int so   = tid * 16;          // base byte offset in 16KB tile
  const int fragswz = (l15 & 7) << 4; // read-side XOR (row&7)<<4

  f32x4 acc[4][4];
#pragma unroll
  for (int i = 0; i < 4; ++i)
#pragma unroll
    for (int j = 0; j < 4; ++j) {
      acc[i][j][0] = 0.f; acc[i][j][1] = 0.f; acc[i][j][2] = 0.f; acc[i][j][3] = 0.f;
    }

#pragma unroll
  for (int pass = 0; pass < 2; ++pass) {
    const ushort* A = pass ? A2 : A1;
    const ushort* B = pass ? B2 : B1;
    const int K = pass ? K2 : K1;
    if (K == 0) continue;
    for (int k0 = 0; k0 < K; k0 += 64) {
      // stage A[128][64] and B[128][64] tiles (16KB each, 4 GLD16/thread/matrix)
#pragma unroll
      for (int it = 0; it < 4; ++it) {
        int o = so + it * 4096;        // linear LDS byte offset
        int row = o >> 7;              // 128 bytes per row
        int colb = o & 127;            // multiple of 16
        int gcolb = colb ^ ((row & 7) << 4);   // inverse pre-swizzle on source
        const ushort* ga = A + (size_t)(m0 + row) * K + k0 + (gcolb >> 1);
        GLD16(ga, (char*)lsA + o);
        const ushort* gb = B + (size_t)(n0 + row) * K + k0 + (gcolb >> 1);
        GLD16(gb, (char*)lsB + o);
      }
      __syncthreads();
#pragma unroll
      for (int kk = 0; kk < 2; ++kk) {
        const int cb = ((kk * 64 + lg * 16) ^ fragswz) >> 1;  // swizzled ushort col
        s16x8 af[4], bfr[4];
#pragma unroll
        for (int i = 0; i < 4; ++i)
          af[i] = *(const s16x8*)&lsA[(wr * 64 + i * 16 + l15) * 64 + cb];
#pragma unroll
        for (int j = 0; j < 4; ++j)
          bfr[j] = *(const s16x8*)&lsB[(wc * 64 + j * 16 + l15) * 64 + cb];
#pragma unroll
        for (int i = 0; i < 4; ++i)
#pragma unroll
          for (int j = 0; j < 4; ++j)
            acc[i][j] = __builtin_amdgcn_mfma_f32_16x16x32_bf16(af[i], bfr[j], acc[i][j], 0, 0, 0);
      }
      __syncthreads();
    }
  }

#pragma unroll
  for (int j = 0; j < 4; ++j) {
    int col = n0 + wc * 64 + j * 16 + l15;
    float bv = bias ? b2f(bias[col]) : 0.f;
#pragma unroll
    for (int i = 0; i < 4; ++i) {
      int rbase = m0 + wr * 64 + i * 16 + lg * 4;
#pragma unroll
      for (int r = 0; r < 4; ++r) {
        float v = acc[i][j][r] + bv;
        if (do_relu) v = fmaxf(v, 0.f);
        size_t idx = (size_t)(rbase + r) * N + col;
        if (Cf) {
          if (fl) Cf[idx] = v;
          else    C[idx] = f2b(v);
        } else {
          C[idx] = f2b(v);
        }
      }
    }
  }
}

// ---------------- kriging gather (reads dual-dtype h region of d_out) ----------------
__global__ void gather_out(const ushort* __restrict__ hb, const float* __restrict__ hf,
                           const int* __restrict__ map_id, void* __restrict__ dout,
                           const int* __restrict__ flag,
                           int K, int num_nodes, int total, int N) {
  int i = blockIdx.x * 256 + threadIdx.x;
  if (i >= total) return;
  int f = i & 127;
  int row = i >> 7;
  int b = row / K;
  unsigned node = (unsigned)(b * num_nodes + map_id[row]);
  bool ok = node < (unsigned)N;
  if (*flag) {
    ((float*)dout)[i] = ok ? hf[(size_t)node * 128 + f] : 0.f;
  } else {
    ((ushort*)dout)[i] = ok ? hb[(size_t)node * 128 + f] : (ushort)0;
  }
}

extern "C" void kernel_launch(void* const* d_in, const int* in_sizes, int n_in,
                              void* d_out, int out_size, void* d_ws, size_t ws_size,
                              hipStream_t stream) {
  const void* x    = d_in[0];
  const int*  ei   = (const int*)d_in[1];
  const int*  mapi = (const int*)d_in[2];
  const void* Wp1  = d_in[4];
  const void* bp1  = d_in[5];
  const void* Wl1  = d_in[6];
  const void* bl1  = d_in[7];
  const void* Wr1  = d_in[8];
  const void* Wp2  = d_in[9];
  const void* bp2  = d_in[10];
  const void* Wl2  = d_in[11];
  const void* bl2  = d_in[12];
  const void* Wr2  = d_in[13];
  const void* Wlin = d_in[14];
  const void* blin = d_in[15];

  const int NN = in_sizes[0] / 256;   // 80000
  const int E  = in_sizes[1] / 2;     // 1.28M
  const int MAPROWS = in_sizes[2];    // 40000
  const int BS = 16;
  const int NUM_NODES = NN / BS;      // 5000
  const int KMAP = MAPROWS / BS;      // 2500
  const int NBUCK = (NN + 511) >> 9;  // 157 buckets of 512 nodes
  const int* src = ei;
  const int* dst = ei + E;

  ushort* houtB = (ushort*)d_out + (size_t)MAPROWS * 128;
  float*  houtF = (float*)d_out + (size_t)MAPROWS * 128;

  int2* pairs = (int2*)((char*)d_out + (size_t)MAPROWS * 128 * 4);

  char* sc = (char*)d_out;
  auto carve_sc = [&](size_t bytes) {
    char* p = sc; sc += (bytes + 255) & ~(size_t)255; return p;
  };
  ushort* Wp1T  = (ushort*)carve_sc(256 * 256 * 2);
  ushort* Wl1T  = (ushort*)carve_sc(256 * 256 * 2);
  ushort* Wr1T  = (ushort*)carve_sc(256 * 256 * 2);
  ushort* Wp2T  = (ushort*)carve_sc(256 * 256 * 2);
  ushort* Wl2T  = (ushort*)carve_sc(128 * 256 * 2);
  ushort* Wr2T  = (ushort*)carve_sc(128 * 256 * 2);
  ushort* WlinT = (ushort*)carve_sc(128 * 128 * 2);
  ushort* bp1c  = (ushort*)carve_sc(256 * 2);
  ushort* bl1c  = (ushort*)carve_sc(256 * 2);
  ushort* bp2c  = (ushort*)carve_sc(256 * 2);
  ushort* bl2c  = (ushort*)carve_sc(128 * 2);
  ushort* blinc = (ushort*)carve_sc(128 * 2);
  int* deg    = (int*)carve_sc((size_t)NN * 4);
  int* rowptr = (int*)carve_sc(((size_t)NN + 1) * 4);
  int* pos    = (int*)carve_sc((size_t)NN * 4);
  int* eidx   = (int*)carve_sc((size_t)E * 4);
  int* bsum   = (int*)carve_sc(1024);
  int* ebsum  = (int*)carve_sc(1024);
  int* bcnt   = (int*)carve_sc(2048);
  int* bscan  = (int*)carve_sc(2048 + 4);
  int* bpos   = (int*)carve_sc(2048);

  char* w = (char*)d_ws;
  auto carve = [&](size_t bytes) {
    char* p = w; w += (bytes + 255) & ~(size_t)255; return p;
  };
  int*    flag = (int*)carve(256);
  ushort* xb   = (ushort*)carve((size_t)NN * 256 * 2);  // x_bf16 -> mean2
  ushort* bA   = (ushort*)carve((size_t)NN * 256 * 2);  // xp1 -> h1
  ushort* bB   = (ushort*)carve((size_t)NN * 256 * 2);  // mean1 -> xp2 -> h2

  // --- dtype detect + conversions ---
  detect_dtype<<<dim3(1), 256, 0, stream>>>((const ushort*)x, flag);
  convert_x<<<dim3((NN * 256 / 8 + 255) / 256), 256, 0, stream>>>(x, xb, flag, NN * 256);

  WPack wp;
  wp.d[0] = {Wp1, Wp1T, 256, 256};
  wp.d[1] = {Wl1, Wl1T, 256, 256};
  wp.d[2] = {Wr1, Wr1T, 256, 256};
  wp.d[3] = {Wp2, Wp2T, 256, 256};
  wp.d[4] = {Wl2, Wl2T, 256, 128};
  wp.d[5] = {Wr2, Wr2T, 256, 128};
  wp.d[6] = {Wlin, WlinT, 128, 128};
  transpose_convert_all<<<dim3(256, 7), 256, 0, stream>>>(wp, flag);

  BPack bp;
  bp.d[0] = {bp1, bp1c, 256, 1};
  bp.d[1] = {bl1, bl1c, 256, 1};
  bp.d[2] = {bp2, bp2c, 256, 1};
  bp.d[3] = {bl2, bl2c, 128, 1};
  bp.d[4] = {blin, blinc, 128, 1};
  convert_vec_all<<<dim3(1, 5), 256, 0, stream>>>(bp, flag);

  // --- CSR build (two-level counting sort) ---
  hipMemsetAsync(deg, 0, (size_t)NN * 4, stream);
  hipMemsetAsync(bcnt, 0, 2048, stream);
  hist_bucket_kernel<<<dim3((E + 2047) / 2048), 256, 0, stream>>>(dst, deg, bcnt, E, NN, NBUCK);
  scan_buckets<<<dim3(1), 256, 0, stream>>>(bcnt, bscan, bpos, NBUCK);
  int SB = (NN + 1023) / 1024;
  scan_phaseA<<<dim3(SB), 256, 0, stream>>>(deg, bsum, NN);
  scan_phaseB<<<dim3(1), 256, 0, stream>>>(bsum, ebsum, rowptr, SB, NN);
  scan_phaseC<<<dim3(SB), 256, 0, stream>>>(deg, ebsum, rowptr, pos, NN);
  bin_scatter<<<dim3((E + 4095) / 4096), 256, 0, stream>>>(src, dst, bpos, pairs, E, NN, NBUCK);
  final_scatter<<<dim3(NBUCK * FS_SPLIT), 256, 0, stream>>>(pairs, bscan, pos, eidx, E);

  dim3 blk(256);
  dim3 g256(NN / 128, 2);   // N=256
  dim3 g128(NN / 128, 1);   // N=128
  dim3 gagg((NN + 3) / 4);

  // --- layer 1 ---
  gemm_bf16<<<g256, blk, 0, stream>>>(xb, Wp1T, nullptr, nullptr, bp1c, bA,
                                      nullptr, nullptr, NN, 256, 256, 0, 1);        // xp1
  agg_mean_v3<<<gagg, blk, 0, stream>>>(bA, rowptr, eidx, bB, NN);                  // mean1
  gemm_bf16<<<g256, blk, 0, stream>>>(bB, Wl1T, xb, Wr1T, bl1c, bA,
                                      nullptr, nullptr, NN, 256, 256, 256, 1);      // h1

  // --- layer 2 ---
  gemm_bf16<<<g256, blk, 0, stream>>>(bA, Wp2T, nullptr, nullptr, bp2c, bB,
                                      nullptr, nullptr, NN, 256, 256, 0, 1);        // xp2
  agg_mean_v3<<<gagg, blk, 0, stream>>>(bB, rowptr, eidx, xb, NN);                  // mean2
  gemm_bf16<<<g128, blk, 0, stream>>>(xb, Wl2T, bA, Wr2T, bl2c, bB,
                                      nullptr, nullptr, NN, 128, 256, 256, 1);      // h2

  // --- final linear: write dual-dtype h straight into d_out h region ---
  gemm_bf16<<<g128, blk, 0, stream>>>(bB, WlinT, nullptr, nullptr, blinc, houtB,
                                      houtF, flag, NN, 128, 128, 0, 0);

  // --- kriging gather -> d_out local_feat region (overwrites scratch, last use) ---
  int total = MAPROWS * 128;
  gather_out<<<dim3((total + 255) / 256), 256, 0, stream>>>(houtB, houtF, mapi, d_out,
                                                            flag, KMAP, NUM_NODES, total, NN);
}

// Round 11
// 473.106 us; speedup vs baseline: 1.0816x; 1.0424x over previous
//
#include <hip/hip_runtime.h>
#include <hip/hip_bf16.h>

typedef __attribute__((ext_vector_type(8))) short s16x8;
typedef __attribute__((ext_vector_type(8))) ushort u16x8;
typedef __attribute__((ext_vector_type(4))) float f32x4;

static __device__ __forceinline__ float b2f(ushort u) {
  union { float f; unsigned bits; } v; v.bits = ((unsigned)u) << 16; return v.f;
}
static __device__ __forceinline__ ushort f2b(float f) {
  __hip_bfloat16 h = __float2bfloat16(f);
  return *reinterpret_cast<ushort*>(&h);
}

// ---------------- dtype detector ----------------
__global__ void detect_dtype(const ushort* __restrict__ xraw, int* __restrict__ flag) {
  __shared__ int cnt;
  if (threadIdx.x == 0) cnt = 0;
  __syncthreads();
  ushort u = xraw[threadIdx.x];
  int e = (u >> 7) & 0xFF;
  if (e >= 113 && e <= 141) atomicAdd(&cnt, 1);
  __syncthreads();
  if (threadIdx.x == 0) *flag = (cnt >= 224) ? 0 : 1;
}

// ---------------- input conversion (dual path, 8 elems/thread) ----------------
__global__ void convert_x(const void* __restrict__ xin, ushort* __restrict__ xb,
                          const int* __restrict__ flag, int n) {
  int i = blockIdx.x * 256 + threadIdx.x;
  int base = i * 8;
  if (base >= n) return;
  if (*flag) {
    const float4 v0 = ((const float4*)xin)[i * 2];
    const float4 v1 = ((const float4*)xin)[i * 2 + 1];
    u16x8 o;
    o[0] = f2b(v0.x); o[1] = f2b(v0.y); o[2] = f2b(v0.z); o[3] = f2b(v0.w);
    o[4] = f2b(v1.x); o[5] = f2b(v1.y); o[6] = f2b(v1.z); o[7] = f2b(v1.w);
    ((u16x8*)xb)[i] = o;
  } else {
    ((u16x8*)xb)[i] = ((const u16x8*)xin)[i];
  }
}

// ---------------- batched weight transpose+convert ----------------
struct WDesc { const void* src; ushort* dst; int R, C; };
struct WPack { WDesc d[7]; };

__global__ void transpose_convert_all(WPack p, const int* __restrict__ flag) {
  const WDesc& d = p.d[blockIdx.y];
  int i = blockIdx.x * 256 + threadIdx.x;
  if (i >= d.R * d.C) return;
  int r = i / d.C, c = i % d.C;
  ushort v = (*flag) ? f2b(((const float*)d.src)[i]) : ((const ushort*)d.src)[i];
  d.dst[c * d.R + r] = v;
}

struct BPack { WDesc d[5]; };
__global__ void convert_vec_all(BPack p, const int* __restrict__ flag) {
  const WDesc& d = p.d[blockIdx.y];
  int i = threadIdx.x;
  if (i >= d.R) return;
  d.dst[i] = (*flag) ? f2b(((const float*)d.src)[i]) : ((const ushort*)d.src)[i];
}

// ---------------- CSR build (two-level counting sort) ----------------
__global__ __launch_bounds__(256)
void hist_bucket_kernel(const int* __restrict__ dst, int* __restrict__ deg,
                        int* __restrict__ bcnt, int E, int N, int nbuck) {
  __shared__ int lh[512];
  int t = threadIdx.x;
  for (int i = t; i < nbuck; i += 256) lh[i] = 0;
  __syncthreads();
  int base = blockIdx.x * 2048;
#pragma unroll
  for (int k = 0; k < 8; ++k) {
    int e = base + k * 256 + t;
    if (e < E) {
      unsigned d = (unsigned)dst[e];
      if (d < (unsigned)N) {
        atomicAdd(&deg[d], 1);
        atomicAdd(&lh[d >> 9], 1);
      }
    }
  }
  __syncthreads();
  for (int i = t; i < nbuck; i += 256)
    if (lh[i]) atomicAdd(&bcnt[i], lh[i]);
}

__global__ __launch_bounds__(256)
void scan_buckets(const int* __restrict__ bcnt, int* __restrict__ bscan,
                  int* __restrict__ bpos, int nbuck) {
  int t = threadIdx.x;
  __shared__ int sh[256];
  int v = (t < nbuck) ? bcnt[t] : 0;
  sh[t] = v; __syncthreads();
  for (int off = 1; off < 256; off <<= 1) {
    int u = (t >= off) ? sh[t - off] : 0;
    __syncthreads();
    sh[t] += u;
    __syncthreads();
  }
  if (t < nbuck) { int ex = sh[t] - v; bscan[t] = ex; bpos[t] = ex; }
  if (t == nbuck - 1) bscan[nbuck] = sh[t];
}

__global__ __launch_bounds__(256)
void bin_scatter(const int* __restrict__ src, const int* __restrict__ dstl,
                 int* __restrict__ bpos, int2* __restrict__ pairs,
                 int E, int N, int nbuck) {
  __shared__ int lh[512];
  __shared__ int lbase[512];
  int t = threadIdx.x;
  for (int i = t; i < nbuck; i += 256) lh[i] = 0;
  __syncthreads();
  int base = blockIdx.x * 4096;
#pragma unroll
  for (int k = 0; k < 16; ++k) {
    int e = base + k * 256 + t;
    if (e < E) {
      unsigned d = (unsigned)dstl[e];
      if (d < (unsigned)N) atomicAdd(&lh[d >> 9], 1);
    }
  }
  __syncthreads();
  for (int i = t; i < nbuck; i += 256) {
    int c = lh[i];
    lbase[i] = c ? atomicAdd(&bpos[i], c) : 0;
    lh[i] = 0;
  }
  __syncthreads();
#pragma unroll
  for (int k = 0; k < 16; ++k) {
    int e = base + k * 256 + t;
    if (e < E) {
      unsigned d = (unsigned)dstl[e];
      if (d < (unsigned)N) {
        int b = d >> 9;
        int r = atomicAdd(&lh[b], 1);
        pairs[lbase[b] + r] = make_int2(src[e], (int)d);
      }
    }
  }
}

#define FS_SPLIT 4
__global__ __launch_bounds__(256)
void final_scatter(const int2* __restrict__ pairs, const int* __restrict__ bscan,
                   int* __restrict__ pos, int* __restrict__ eidx, int E) {
  int b = blockIdx.x / FS_SPLIT;
  int part = blockIdx.x % FS_SPLIT;
  int s = bscan[b], e = bscan[b + 1];
  int len = e - s;
  int per = (len + FS_SPLIT - 1) / FS_SPLIT;
  int lo = s + part * per;
  int hi = min(lo + per, e);
  for (int i = lo + threadIdx.x; i < hi; i += 256) {
    int2 p = pairs[i];
    unsigned q = (unsigned)atomicAdd(&pos[p.y], 1);
    if (q < (unsigned)E) eidx[q] = p.x;
  }
}

// 3-phase device-wide exclusive scan of deg -> rowptr/pos
__global__ __launch_bounds__(256)
void scan_phaseA(const int* __restrict__ deg, int* __restrict__ bsum, int N) {
  int b = blockIdx.x, t = threadIdx.x;
  int i0 = b * 1024 + t * 4;
  int s = 0;
#pragma unroll
  for (int k = 0; k < 4; ++k) {
    int i = i0 + k;
    if (i < N) s += deg[i];
  }
  __shared__ int red[256];
  red[t] = s; __syncthreads();
  for (int off = 128; off > 0; off >>= 1) {
    if (t < off) red[t] += red[t + off];
    __syncthreads();
  }
  if (t == 0) bsum[b] = red[0];
}

__global__ __launch_bounds__(256)
void scan_phaseB(const int* __restrict__ bsum, int* __restrict__ ebsum,
                 int* __restrict__ rowptr, int B, int N) {
  int t = threadIdx.x;
  __shared__ int sh[256];
  int v = (t < B) ? bsum[t] : 0;
  sh[t] = v; __syncthreads();
  for (int off = 1; off < 256; off <<= 1) {
    int u = (t >= off) ? sh[t - off] : 0;
    __syncthreads();
    sh[t] += u;
    __syncthreads();
  }
  if (t < B) ebsum[t] = sh[t] - v;
  if (t == B - 1) rowptr[N] = sh[t];
}

__global__ __launch_bounds__(256)
void scan_phaseC(const int* __restrict__ deg, const int* __restrict__ ebsum,
                 int* __restrict__ rowptr, int* __restrict__ pos, int N) {
  int b = blockIdx.x, t = threadIdx.x;
  int i0 = b * 1024 + t * 4;
  int v[4]; int s = 0;
#pragma unroll
  for (int k = 0; k < 4; ++k) {
    int i = i0 + k;
    v[k] = (i < N) ? deg[i] : 0;
    s += v[k];
  }
  __shared__ int sh[256];
  sh[t] = s; __syncthreads();
  for (int off = 1; off < 256; off <<= 1) {
    int u = (t >= off) ? sh[t - off] : 0;
    __syncthreads();
    sh[t] += u;
    __syncthreads();
  }
  int run = ebsum[b] + sh[t] - s;
#pragma unroll
  for (int k = 0; k < 4; ++k) {
    int i = i0 + k;
    if (i < N) { rowptr[i] = run; pos[i] = run; run += v[k]; }
  }
}

// ---------------- mean aggregation v3 (wave-per-node, 16B/lane) ----------------
__global__ __launch_bounds__(256)
void agg_mean_v3(const ushort* __restrict__ xp, const int* __restrict__ rowptr,
                 const int* __restrict__ eidx, ushort* __restrict__ mean, int NN) {
  int node = blockIdx.x * 4 + (threadIdx.x >> 6);
  if (node >= NN) return;
  int lane = threadIdx.x & 63;
  int half = lane >> 5;
  int l32 = lane & 31;
  int s = rowptr[node], e = rowptr[node + 1];
  float a[8];
#pragma unroll
  for (int k = 0; k < 8; ++k) a[k] = 0.f;

  for (int base = s; base < e; base += 64) {
    int cnt = min(64, e - base);
    int my = (lane < cnt) ? eidx[base + lane] : 0;
    int full = cnt >> 1;
#pragma unroll 2
    for (int it = 0; it < full; ++it) {
      int sn = __shfl(my, 2 * it + half);
      u16x8 v = *(const u16x8*)&xp[(size_t)sn * 256 + l32 * 8];
#pragma unroll
      for (int k = 0; k < 8; ++k) a[k] += b2f(v[k]);
    }
    if (cnt & 1) {
      int sn = __shfl(my, cnt - 1);
      if (half == 0) {
        u16x8 v = *(const u16x8*)&xp[(size_t)sn * 256 + l32 * 8];
#pragma unroll
        for (int k = 0; k < 8; ++k) a[k] += b2f(v[k]);
      }
    }
  }
#pragma unroll
  for (int k = 0; k < 8; ++k) a[k] += __shfl_xor(a[k], 32);

  int c = e - s; if (c < 1) c = 1;
  float inv = 1.f / (float)c;
  if (half == 0) {
    u16x8 o;
#pragma unroll
    for (int k = 0; k < 8; ++k) o[k] = f2b(a[k] * inv);
    *(u16x8*)&mean[(size_t)node * 256 + l32 * 8] = o;
  }
}

// ---------------- MFMA GEMM v3: BK=64 swizzled staging + LDS-transposed epilogue ----
#define GLD16(g, l) \
  __builtin_amdgcn_global_load_lds((const __attribute__((address_space(1))) void*)(g), \
                                   (__attribute__((address_space(3))) void*)(l), 16, 0, 0)

__global__ __launch_bounds__(256, 3)
void gemm_bf16(const ushort* __restrict__ A1, const ushort* __restrict__ B1,
               const ushort* __restrict__ A2, const ushort* __restrict__ B2,
               const ushort* __restrict__ bias, ushort* __restrict__ C,
               int M, int N, int K1, int K2, int do_relu) {
  __shared__ __align__(16) ushort lsAB[2][128 * 64];   // staging; reused as [128][128] tile
  const int tid = threadIdx.x;
  const int lane = tid & 63;
  const int wid = tid >> 6;
  const int wr = wid >> 1, wc = wid & 1;
  const int m0 = blockIdx.x * 128;
  const int n0 = blockIdx.y * 128;
  const int l15 = lane & 15;
  const int lg = lane >> 4;
  const int so = tid * 16;
  const int fragswz = (l15 & 7) << 4;

  f32x4 acc[4][4];
#pragma unroll
  for (int i = 0; i < 4; ++i)
#pragma unroll
    for (int j = 0; j < 4; ++j) {
      acc[i][j][0] = 0.f; acc[i][j][1] = 0.f; acc[i][j][2] = 0.f; acc[i][j][3] = 0.f;
    }

#pragma unroll
  for (int pass = 0; pass < 2; ++pass) {
    const ushort* A = pass ? A2 : A1;
    const ushort* B = pass ? B2 : B1;
    const int K = pass ? K2 : K1;
    if (K == 0) continue;
    for (int k0 = 0; k0 < K; k0 += 64) {
#pragma unroll
      for (int it = 0; it < 4; ++it) {
        int o = so + it * 4096;
        int row = o >> 7;
        int colb = o & 127;
        int gcolb = colb ^ ((row & 7) << 4);
        const ushort* ga = A + (size_t)(m0 + row) * K + k0 + (gcolb >> 1);
        GLD16(ga, (char*)lsAB[0] + o);
        const ushort* gb = B + (size_t)(n0 + row) * K + k0 + (gcolb >> 1);
        GLD16(gb, (char*)lsAB[1] + o);
      }
      __syncthreads();
#pragma unroll
      for (int kk = 0; kk < 2; ++kk) {
        const int cb = ((kk * 64 + lg * 16) ^ fragswz) >> 1;
        s16x8 af[4], bfr[4];
#pragma unroll
        for (int i = 0; i < 4; ++i)
          af[i] = *(const s16x8*)&lsAB[0][(wr * 64 + i * 16 + l15) * 64 + cb];
#pragma unroll
        for (int j = 0; j < 4; ++j)
          bfr[j] = *(const s16x8*)&lsAB[1][(wc * 64 + j * 16 + l15) * 64 + cb];
#pragma unroll
        for (int i = 0; i < 4; ++i)
#pragma unroll
          for (int j = 0; j < 4; ++j)
            acc[i][j] = __builtin_amdgcn_mfma_f32_16x16x32_bf16(af[i], bfr[j], acc[i][j], 0, 0, 0);
      }
      __syncthreads();
    }
  }

  // ---- epilogue: acc -> swizzled LDS tile -> coalesced u16x8 stores ----
  ushort* tile = (ushort*)lsAB;   // [128][128]
#pragma unroll
  for (int j = 0; j < 4; ++j) {
    int col = wc * 64 + j * 16 + l15;
    float bv = bias ? b2f(bias[n0 + col]) : 0.f;
#pragma unroll
    for (int i = 0; i < 4; ++i) {
#pragma unroll
      for (int r = 0; r < 4; ++r) {
        int row = wr * 64 + i * 16 + lg * 4 + r;
        float v = acc[i][j][r] + bv;
        if (do_relu) v = fmaxf(v, 0.f);
        tile[row * 128 + (col ^ ((row & 7) << 3))] = f2b(v);
      }
    }
  }
  __syncthreads();
#pragma unroll
  for (int t = 0; t < 8; ++t) {
    int id = t * 256 + tid;
    int row = id >> 4;
    int c8 = id & 15;
    u16x8 v = *(const u16x8*)&tile[row * 128 + (c8 ^ (row & 7)) * 8];
    *(u16x8*)&C[(size_t)(m0 + row) * N + n0 + c8 * 8] = v;
  }
}

// ---------------- fused h2-GEMM + final linear -> dual-dtype h output ----------------
// phase1: h2 = relu(mean2@Wl2 + h1@Wr2 + bl2)  (128x128 tile, K=256+256)
// phase2: h = h2 @ Wlin^T + blin               (K=128, h2 tile + Wlin in LDS)
__global__ __launch_bounds__(256, 2)
void gemm_h2_final(const ushort* __restrict__ A1, const ushort* __restrict__ B1,
                   const ushort* __restrict__ A2, const ushort* __restrict__ B2,
                   const ushort* __restrict__ bias2, const ushort* __restrict__ Wlin,
                   const ushort* __restrict__ biasf,
                   ushort* __restrict__ CB, float* __restrict__ CF,
                   const int* __restrict__ flag, int K1, int K2) {
  __shared__ __align__(16) ushort lsAB[2][128 * 64];   // phase1 staging / h2 tile / out tile
  __shared__ __align__(16) ushort lsW[128 * 128];      // WlinT [128][128] swizzled
  const int tid = threadIdx.x;
  const int lane = tid & 63;
  const int wid = tid >> 6;
  const int wr = wid >> 1, wc = wid & 1;
  const int m0 = blockIdx.x * 128;
  const int l15 = lane & 15;
  const int lg = lane >> 4;
  const int so = tid * 16;
  const int fragswz = (l15 & 7) << 4;
  const int fl = *flag;

  // stage WlinT at entry (lsW unused during phase 1; drained by phase-1 barriers)
#pragma unroll
  for (int it = 0; it < 8; ++it) {
    int o = so + it * 4096;
    int row = o >> 8;               // 256B per row
    int colb = o & 255;
    int gcolb = colb ^ ((row & 7) << 4);
    GLD16(Wlin + (size_t)row * 128 + (gcolb >> 1), (char*)lsW + o);
  }

  f32x4 acc[4][4];
#pragma unroll
  for (int i = 0; i < 4; ++i)
#pragma unroll
    for (int j = 0; j < 4; ++j) {
      acc[i][j][0] = 0.f; acc[i][j][1] = 0.f; acc[i][j][2] = 0.f; acc[i][j][3] = 0.f;
    }

#pragma unroll
  for (int pass = 0; pass < 2; ++pass) {
    const ushort* A = pass ? A2 : A1;
    const ushort* B = pass ? B2 : B1;
    const int K = pass ? K2 : K1;
    for (int k0 = 0; k0 < K; k0 += 64) {
#pragma unroll
      for (int it = 0; it < 4; ++it) {
        int o = so + it * 4096;
        int row = o >> 7;
        int colb = o & 127;
        int gcolb = colb ^ ((row & 7) << 4);
        GLD16(A + (size_t)(m0 + row) * K + k0 + (gcolb >> 1), (char*)lsAB[0] + o);
        GLD16(B + (size_t)row * K + k0 + (gcolb >> 1), (char*)lsAB[1] + o);
      }
      __syncthreads();
#pragma unroll
      for (int kk = 0; kk < 2; ++kk) {
        const int cb = ((kk * 64 + lg * 16) ^ fragswz) >> 1;
        s16x8 af[4], bfr[4];
#pragma unroll
        for (int i = 0; i < 4; ++i)
          af[i] = *(const s16x8*)&lsAB[0][(wr * 64 + i * 16 + l15) * 64 + cb];
#pragma unroll
        for (int j = 0; j < 4; ++j)
          bfr[j] = *(const s16x8*)&lsAB[1][(wc * 64 + j * 16 + l15) * 64 + cb];
#pragma unroll
        for (int i = 0; i < 4; ++i)
#pragma unroll
          for (int j = 0; j < 4; ++j)
            acc[i][j] = __builtin_amdgcn_mfma_f32_16x16x32_bf16(af[i], bfr[j], acc[i][j], 0, 0, 0);
      }
      __syncthreads();
    }
  }

  // ---- h2 tile (relu + bias) -> swizzled LDS [128][128] bf16 ----
  ushort* tile = (ushort*)lsAB;
#pragma unroll
  for (int j = 0; j < 4; ++j) {
    int col = wc * 64 + j * 16 + l15;
    float bv = b2f(bias2[col]);
#pragma unroll
    for (int i = 0; i < 4; ++i) {
#pragma unroll
      for (int r = 0; r < 4; ++r) {
        int row = wr * 64 + i * 16 + lg * 4 + r;
        float v = fmaxf(acc[i][j][r] + bv, 0.f);
        tile[row * 128 + (col ^ ((row & 7) << 3))] = f2b(v);
      }
    }
  }
  __syncthreads();

  // ---- phase 2: h = h2_tile @ Wlin^T (K=128, all-LDS) ----
  f32x4 acc2[4][4];
#pragma unroll
  for (int i = 0; i < 4; ++i)
#pragma unroll
    for (int j = 0; j < 4; ++j) {
      acc2[i][j][0] = 0.f; acc2[i][j][1] = 0.f; acc2[i][j][2] = 0.f; acc2[i][j][3] = 0.f;
    }
#pragma unroll
  for (int kk = 0; kk < 4; ++kk) {
    s16x8 af[4], bfr[4];
#pragma unroll
    for (int i = 0; i < 4; ++i) {
      int row = wr * 64 + i * 16 + l15;
      int cb = (kk * 32 + lg * 8) ^ ((row & 7) << 3);
      af[i] = *(const s16x8*)&tile[row * 128 + cb];
    }
#pragma unroll
    for (int j = 0; j < 4; ++j) {
      int row = wc * 64 + j * 16 + l15;
      int cb = (kk * 32 + lg * 8) ^ ((row & 7) << 3);
      bfr[j] = *(const s16x8*)&lsW[row * 128 + cb];
    }
#pragma unroll
    for (int i = 0; i < 4; ++i)
#pragma unroll
      for (int j = 0; j < 4; ++j)
        acc2[i][j] = __builtin_amdgcn_mfma_f32_16x16x32_bf16(af[i], bfr[j], acc2[i][j], 0, 0, 0);
  }
  __syncthreads();   // all reads of tile done before overwrite

  // ---- epilogue: h (bias, no relu) -> tile -> dual-dtype coalesced store ----
#pragma unroll
  for (int j = 0; j < 4; ++j) {
    int col = wc * 64 + j * 16 + l15;
    float bv = b2f(biasf[col]);
#pragma unroll
    for (int i = 0; i < 4; ++i) {
#pragma unroll
      for (int r = 0; r < 4; ++r) {
        int row = wr * 64 + i * 16 + lg * 4 + r;
        tile[row * 128 + (col ^ ((row & 7) << 3))] = f2b(acc2[i][j][r] + bv);
      }
    }
  }
  __syncthreads();
#pragma unroll
  for (int t = 0; t < 8; ++t) {
    int id = t * 256 + tid;
    int row = id >> 4;
    int c8 = id & 15;
    u16x8 v = *(const u16x8*)&tile[row * 128 + (c8 ^ (row & 7)) * 8];
    size_t off = (size_t)(m0 + row) * 128 + c8 * 8;
    if (fl) {
      float4 f0, f1;
      f0.x = b2f(v[0]); f0.y = b2f(v[1]); f0.z = b2f(v[2]); f0.w = b2f(v[3]);
      f1.x = b2f(v[4]); f1.y = b2f(v[5]); f1.z = b2f(v[6]); f1.w = b2f(v[7]);
      *(float4*)&CF[off] = f0;
      *(float4*)&CF[off + 4] = f1;
    } else {
      *(u16x8*)&CB[off] = v;
    }
  }
}

// ---------------- kriging gather ----------------
__global__ void gather_out(const ushort* __restrict__ hb, const float* __restrict__ hf,
                           const int* __restrict__ map_id, void* __restrict__ dout,
                           const int* __restrict__ flag,
                           int K, int num_nodes, int total, int N) {
  int i = blockIdx.x * 256 + threadIdx.x;
  if (i >= total) return;
  int f = i & 127;
  int row = i >> 7;
  int b = row / K;
  unsigned node = (unsigned)(b * num_nodes + map_id[row]);
  bool ok = node < (unsigned)N;
  if (*flag) {
    ((float*)dout)[i] = ok ? hf[(size_t)node * 128 + f] : 0.f;
  } else {
    ((ushort*)dout)[i] = ok ? hb[(size_t)node * 128 + f] : (ushort)0;
  }
}

extern "C" void kernel_launch(void* const* d_in, const int* in_sizes, int n_in,
                              void* d_out, int out_size, void* d_ws, size_t ws_size,
                              hipStream_t stream) {
  const void* x    = d_in[0];
  const int*  ei   = (const int*)d_in[1];
  const int*  mapi = (const int*)d_in[2];
  const void* Wp1  = d_in[4];
  const void* bp1  = d_in[5];
  const void* Wl1  = d_in[6];
  const void* bl1  = d_in[7];
  const void* Wr1  = d_in[8];
  const void* Wp2  = d_in[9];
  const void* bp2  = d_in[10];
  const void* Wl2  = d_in[11];
  const void* bl2  = d_in[12];
  const void* Wr2  = d_in[13];
  const void* Wlin = d_in[14];
  const void* blin = d_in[15];

  const int NN = in_sizes[0] / 256;   // 80000
  const int E  = in_sizes[1] / 2;     // 1.28M
  const int MAPROWS = in_sizes[2];    // 40000
  const int BS = 16;
  const int NUM_NODES = NN / BS;      // 5000
  const int KMAP = MAPROWS / BS;      // 2500
  const int NBUCK = (NN + 511) >> 9;  // 157
  const int* src = ei;
  const int* dst = ei + E;

  ushort* houtB = (ushort*)d_out + (size_t)MAPROWS * 128;
  float*  houtF = (float*)d_out + (size_t)MAPROWS * 128;
  int2* pairs = (int2*)((char*)d_out + (size_t)MAPROWS * 128 * 4);

  char* sc = (char*)d_out;
  auto carve_sc = [&](size_t bytes) {
    char* p = sc; sc += (bytes + 255) & ~(size_t)255; return p;
  };
  ushort* Wp1T  = (ushort*)carve_sc(256 * 256 * 2);
  ushort* Wl1T  = (ushort*)carve_sc(256 * 256 * 2);
  ushort* Wr1T  = (ushort*)carve_sc(256 * 256 * 2);
  ushort* Wp2T  = (ushort*)carve_sc(256 * 256 * 2);
  ushort* Wl2T  = (ushort*)carve_sc(128 * 256 * 2);
  ushort* Wr2T  = (ushort*)carve_sc(128 * 256 * 2);
  ushort* WlinT = (ushort*)carve_sc(128 * 128 * 2);
  ushort* bp1c  = (ushort*)carve_sc(256 * 2);
  ushort* bl1c  = (ushort*)carve_sc(256 * 2);
  ushort* bp2c  = (ushort*)carve_sc(256 * 2);
  ushort* bl2c  = (ushort*)carve_sc(128 * 2);
  ushort* blinc = (ushort*)carve_sc(128 * 2);
  int* deg    = (int*)carve_sc((size_t)NN * 4);
  int* rowptr = (int*)carve_sc(((size_t)NN + 1) * 4);
  int* pos    = (int*)carve_sc((size_t)NN * 4);
  int* eidx   = (int*)carve_sc((size_t)E * 4);
  int* bsum   = (int*)carve_sc(1024);
  int* ebsum  = (int*)carve_sc(1024);
  int* bcnt   = (int*)carve_sc(2048);
  int* bscan  = (int*)carve_sc(2048 + 4);
  int* bpos   = (int*)carve_sc(2048);

  char* w = (char*)d_ws;
  auto carve = [&](size_t bytes) {
    char* p = w; w += (bytes + 255) & ~(size_t)255; return p;
  };
  int*    flag = (int*)carve(256);
  ushort* xb   = (ushort*)carve((size_t)NN * 256 * 2);  // x_bf16 -> mean2
  ushort* bA   = (ushort*)carve((size_t)NN * 256 * 2);  // xp1 -> h1
  ushort* bB   = (ushort*)carve((size_t)NN * 256 * 2);  // mean1 -> xp2

  // --- dtype detect + conversions ---
  detect_dtype<<<dim3(1), 256, 0, stream>>>((const ushort*)x, flag);
  convert_x<<<dim3((NN * 256 / 8 + 255) / 256), 256, 0, stream>>>(x, xb, flag, NN * 256);

  WPack wp;
  wp.d[0] = {Wp1, Wp1T, 256, 256};
  wp.d[1] = {Wl1, Wl1T, 256, 256};
  wp.d[2] = {Wr1, Wr1T, 256, 256};
  wp.d[3] = {Wp2, Wp2T, 256, 256};
  wp.d[4] = {Wl2, Wl2T, 256, 128};
  wp.d[5] = {Wr2, Wr2T, 256, 128};
  wp.d[6] = {Wlin, WlinT, 128, 128};
  transpose_convert_all<<<dim3(256, 7), 256, 0, stream>>>(wp, flag);

  BPack bp;
  bp.d[0] = {bp1, bp1c, 256, 1};
  bp.d[1] = {bl1, bl1c, 256, 1};
  bp.d[2] = {bp2, bp2c, 256, 1};
  bp.d[3] = {bl2, bl2c, 128, 1};
  bp.d[4] = {blin, blinc, 128, 1};
  convert_vec_all<<<dim3(1, 5), 256, 0, stream>>>(bp, flag);

  // --- CSR build ---
  hipMemsetAsync(deg, 0, (size_t)NN * 4, stream);
  hipMemsetAsync(bcnt, 0, 2048, stream);
  hist_bucket_kernel<<<dim3((E + 2047) / 2048), 256, 0, stream>>>(dst, deg, bcnt, E, NN, NBUCK);
  scan_buckets<<<dim3(1), 256, 0, stream>>>(bcnt, bscan, bpos, NBUCK);
  int SB = (NN + 1023) / 1024;
  scan_phaseA<<<dim3(SB), 256, 0, stream>>>(deg, bsum, NN);
  scan_phaseB<<<dim3(1), 256, 0, stream>>>(bsum, ebsum, rowptr, SB, NN);
  scan_phaseC<<<dim3(SB), 256, 0, stream>>>(deg, ebsum, rowptr, pos, NN);
  bin_scatter<<<dim3((E + 4095) / 4096), 256, 0, stream>>>(src, dst, bpos, pairs, E, NN, NBUCK);
  final_scatter<<<dim3(NBUCK * FS_SPLIT), 256, 0, stream>>>(pairs, bscan, pos, eidx, E);

  dim3 blk(256);
  dim3 g256(NN / 128, 2);   // N=256
  dim3 gagg((NN + 3) / 4);

  // --- layer 1 ---
  gemm_bf16<<<g256, blk, 0, stream>>>(xb, Wp1T, nullptr, nullptr, bp1c, bA,
                                      NN, 256, 256, 0, 1);                          // xp1
  agg_mean_v3<<<gagg, blk, 0, stream>>>(bA, rowptr, eidx, bB, NN);                  // mean1
  gemm_bf16<<<g256, blk, 0, stream>>>(bB, Wl1T, xb, Wr1T, bl1c, bA,
                                      NN, 256, 256, 256, 1);                        // h1

  // --- layer 2 ---
  gemm_bf16<<<g256, blk, 0, stream>>>(bA, Wp2T, nullptr, nullptr, bp2c, bB,
                                      NN, 256, 256, 0, 1);                          // xp2
  agg_mean_v3<<<gagg, blk, 0, stream>>>(bB, rowptr, eidx, xb, NN);                  // mean2

  // --- fused h2 + final linear -> dual-dtype h in d_out ---
  gemm_h2_final<<<dim3(NN / 128), blk, 0, stream>>>(xb, Wl2T, bA, Wr2T, bl2c,
                                                    WlinT, blinc, houtB, houtF,
                                                    flag, 256, 256);

  // --- kriging gather ---
  int total = MAPROWS * 128;
  gather_out<<<dim3((total + 255) / 256), 256, 0, stream>>>(houtB, houtF, mapi, d_out,
                                                            flag, KMAP, NUM_NODES, total, NN);
}

// Round 12
// 400.462 us; speedup vs baseline: 1.2778x; 1.1814x over previous
//
#include <hip/hip_runtime.h>
#include <hip/hip_bf16.h>

typedef __attribute__((ext_vector_type(8))) short s16x8;
typedef __attribute__((ext_vector_type(8))) ushort u16x8;
typedef __attribute__((ext_vector_type(4))) float f32x4;

static __device__ __forceinline__ float b2f(ushort u) {
  union { float f; unsigned bits; } v; v.bits = ((unsigned)u) << 16; return v.f;
}
static __device__ __forceinline__ ushort f2b(float f) {
  __hip_bfloat16 h = __float2bfloat16(f);
  return *reinterpret_cast<ushort*>(&h);
}

// ---------------- dtype detector ----------------
__global__ void detect_dtype(const ushort* __restrict__ xraw, int* __restrict__ flag) {
  __shared__ int cnt;
  if (threadIdx.x == 0) cnt = 0;
  __syncthreads();
  ushort u = xraw[threadIdx.x];
  int e = (u >> 7) & 0xFF;
  if (e >= 113 && e <= 141) atomicAdd(&cnt, 1);
  __syncthreads();
  if (threadIdx.x == 0) *flag = (cnt >= 224) ? 0 : 1;
}

// ---------------- input conversion (dual path, 8 elems/thread) ----------------
__global__ void convert_x(const void* __restrict__ xin, ushort* __restrict__ xb,
                          const int* __restrict__ flag, int n) {
  int i = blockIdx.x * 256 + threadIdx.x;
  int base = i * 8;
  if (base >= n) return;
  if (*flag) {
    const float4 v0 = ((const float4*)xin)[i * 2];
    const float4 v1 = ((const float4*)xin)[i * 2 + 1];
    u16x8 o;
    o[0] = f2b(v0.x); o[1] = f2b(v0.y); o[2] = f2b(v0.z); o[3] = f2b(v0.w);
    o[4] = f2b(v1.x); o[5] = f2b(v1.y); o[6] = f2b(v1.z); o[7] = f2b(v1.w);
    ((u16x8*)xb)[i] = o;
  } else {
    ((u16x8*)xb)[i] = ((const u16x8*)xin)[i];
  }
}

// ---------------- batched weight transpose+convert ----------------
struct WDesc { const void* src; ushort* dst; int R, C; };
struct WPack { WDesc d[7]; };

__global__ void transpose_convert_all(WPack p, const int* __restrict__ flag) {
  const WDesc& d = p.d[blockIdx.y];
  int i = blockIdx.x * 256 + threadIdx.x;
  if (i >= d.R * d.C) return;
  int r = i / d.C, c = i % d.C;
  ushort v = (*flag) ? f2b(((const float*)d.src)[i]) : ((const ushort*)d.src)[i];
  d.dst[c * d.R + r] = v;
}

struct BPack { WDesc d[5]; };
__global__ void convert_vec_all(BPack p, const int* __restrict__ flag) {
  const WDesc& d = p.d[blockIdx.y];
  int i = threadIdx.x;
  if (i >= d.R) return;
  d.dst[i] = (*flag) ? f2b(((const float*)d.src)[i]) : ((const ushort*)d.src)[i];
}

// ---------------- CSR build (two-level counting sort, LDS-finalized) ----------------
// Bucket = dst >> 9 (512 nodes/bucket).

// bucket counts only (LDS histogram; no per-node global atomics)
__global__ __launch_bounds__(256)
void hist_bucket_kernel(const int* __restrict__ dst, int* __restrict__ bcnt,
                        int E, int N, int nbuck) {
  __shared__ int lh[512];
  int t = threadIdx.x;
  for (int i = t; i < nbuck; i += 256) lh[i] = 0;
  __syncthreads();
  int base = blockIdx.x * 2048;
#pragma unroll
  for (int k = 0; k < 8; ++k) {
    int e = base + k * 256 + t;
    if (e < E) {
      unsigned d = (unsigned)dst[e];
      if (d < (unsigned)N) atomicAdd(&lh[d >> 9], 1);
    }
  }
  __syncthreads();
  for (int i = t; i < nbuck; i += 256)
    if (lh[i]) atomicAdd(&bcnt[i], lh[i]);
}

__global__ __launch_bounds__(256)
void scan_buckets(const int* __restrict__ bcnt, int* __restrict__ bscan,
                  int* __restrict__ bpos, int* __restrict__ rowptr,
                  int nbuck, int NN) {
  int t = threadIdx.x;
  __shared__ int sh[256];
  int v = (t < nbuck) ? bcnt[t] : 0;
  sh[t] = v; __syncthreads();
  for (int off = 1; off < 256; off <<= 1) {
    int u = (t >= off) ? sh[t - off] : 0;
    __syncthreads();
    sh[t] += u;
    __syncthreads();
  }
  if (t < nbuck) { int ex = sh[t] - v; bscan[t] = ex; bpos[t] = ex; }
  if (t == nbuck - 1) { bscan[nbuck] = sh[t]; rowptr[NN] = sh[t]; }
}

// bin edges into bucket-grouped (src,dst) pairs
__global__ __launch_bounds__(256)
void bin_scatter(const int* __restrict__ src, const int* __restrict__ dstl,
                 int* __restrict__ bpos, int2* __restrict__ pairs,
                 int E, int N, int nbuck) {
  __shared__ int lh[512];
  __shared__ int lbase[512];
  int t = threadIdx.x;
  for (int i = t; i < nbuck; i += 256) lh[i] = 0;
  __syncthreads();
  int base = blockIdx.x * 4096;
#pragma unroll
  for (int k = 0; k < 16; ++k) {
    int e = base + k * 256 + t;
    if (e < E) {
      unsigned d = (unsigned)dstl[e];
      if (d < (unsigned)N) atomicAdd(&lh[d >> 9], 1);
    }
  }
  __syncthreads();
  for (int i = t; i < nbuck; i += 256) {
    int c = lh[i];
    lbase[i] = c ? atomicAdd(&bpos[i], c) : 0;
    lh[i] = 0;
  }
  __syncthreads();
#pragma unroll
  for (int k = 0; k < 16; ++k) {
    int e = base + k * 256 + t;
    if (e < E) {
      unsigned d = (unsigned)dstl[e];
      if (d < (unsigned)N) {
        int b = d >> 9;
        int r = atomicAdd(&lh[b], 1);
        pairs[lbase[b] + r] = make_int2(src[e], (int)d);
      }
    }
  }
}

// per-bucket LDS counting sort: builds rowptr slice + eidx, no global atomics.
// One block per bucket; pairs in [bscan[b], bscan[b+1]) all have dst>>9 == b.
__global__ __launch_bounds__(256)
void bucket_finalize(const int2* __restrict__ pairs, const int* __restrict__ bscan,
                     int* __restrict__ rowptr, int* __restrict__ eidx, int NN) {
  __shared__ int hist[512];
  __shared__ int offp[512];
  __shared__ int sh[256];
  int b = blockIdx.x;
  int t = threadIdx.x;
  int s = bscan[b], e = bscan[b + 1];
  hist[t] = 0; hist[t + 256] = 0;
  __syncthreads();
  for (int i = s + t; i < e; i += 256)
    atomicAdd(&hist[pairs[i].y & 511], 1);
  __syncthreads();
  // exclusive scan over 512 entries (2 per thread)
  int v0 = hist[2 * t], v1 = hist[2 * t + 1];
  int sum2 = v0 + v1;
  sh[t] = sum2; __syncthreads();
  for (int off = 1; off < 256; off <<= 1) {
    int u = (t >= off) ? sh[t - off] : 0;
    __syncthreads();
    sh[t] += u;
    __syncthreads();
  }
  int ex = sh[t] - sum2;
  int o0 = s + ex;
  int o1 = o0 + v0;
  offp[2 * t] = o0;
  offp[2 * t + 1] = o1;
  int node0 = b * 512 + 2 * t;
  if (node0 <= NN)     rowptr[node0] = o0;
  if (node0 + 1 <= NN) rowptr[node0 + 1] = o1;
  __syncthreads();
  for (int i = s + t; i < e; i += 256) {
    int2 p = pairs[i];
    int r = atomicAdd(&offp[p.y & 511], 1);
    eidx[r] = p.x;
  }
}

// ---------------- mean aggregation v3 (wave-per-node, 16B/lane) ----------------
__global__ __launch_bounds__(256)
void agg_mean_v3(const ushort* __restrict__ xp, const int* __restrict__ rowptr,
                 const int* __restrict__ eidx, ushort* __restrict__ mean, int NN) {
  int node = blockIdx.x * 4 + (threadIdx.x >> 6);
  if (node >= NN) return;
  int lane = threadIdx.x & 63;
  int half = lane >> 5;
  int l32 = lane & 31;
  int s = rowptr[node], e = rowptr[node + 1];
  float a[8];
#pragma unroll
  for (int k = 0; k < 8; ++k) a[k] = 0.f;

  for (int base = s; base < e; base += 64) {
    int cnt = min(64, e - base);
    int my = (lane < cnt) ? eidx[base + lane] : 0;
    int full = cnt >> 1;
#pragma unroll 2
    for (int it = 0; it < full; ++it) {
      int sn = __shfl(my, 2 * it + half);
      u16x8 v = *(const u16x8*)&xp[(size_t)sn * 256 + l32 * 8];
#pragma unroll
      for (int k = 0; k < 8; ++k) a[k] += b2f(v[k]);
    }
    if (cnt & 1) {
      int sn = __shfl(my, cnt - 1);
      if (half == 0) {
        u16x8 v = *(const u16x8*)&xp[(size_t)sn * 256 + l32 * 8];
#pragma unroll
        for (int k = 0; k < 8; ++k) a[k] += b2f(v[k]);
      }
    }
  }
#pragma unroll
  for (int k = 0; k < 8; ++k) a[k] += __shfl_xor(a[k], 32);

  int c = e - s; if (c < 1) c = 1;
  float inv = 1.f / (float)c;
  if (half == 0) {
    u16x8 o;
#pragma unroll
    for (int k = 0; k < 8; ++k) o[k] = f2b(a[k] * inv);
    *(u16x8*)&mean[(size_t)node * 256 + l32 * 8] = o;
  }
}

// ---------------- MFMA GEMM v3: BK=64 swizzled staging + LDS-transposed epilogue ----
#define GLD16(g, l) \
  __builtin_amdgcn_global_load_lds((const __attribute__((address_space(1))) void*)(g), \
                                   (__attribute__((address_space(3))) void*)(l), 16, 0, 0)

__global__ __launch_bounds__(256, 3)
void gemm_bf16(const ushort* __restrict__ A1, const ushort* __restrict__ B1,
               const ushort* __restrict__ A2, const ushort* __restrict__ B2,
               const ushort* __restrict__ bias, ushort* __restrict__ C,
               int M, int N, int K1, int K2, int do_relu) {
  __shared__ __align__(16) ushort lsAB[2][128 * 64];
  const int tid = threadIdx.x;
  const int lane = tid & 63;
  const int wid = tid >> 6;
  const int wr = wid >> 1, wc = wid & 1;
  const int m0 = blockIdx.x * 128;
  const int n0 = blockIdx.y * 128;
  const int l15 = lane & 15;
  const int lg = lane >> 4;
  const int so = tid * 16;
  const int fragswz = (l15 & 7) << 4;

  f32x4 acc[4][4];
#pragma unroll
  for (int i = 0; i < 4; ++i)
#pragma unroll
    for (int j = 0; j < 4; ++j) {
      acc[i][j][0] = 0.f; acc[i][j][1] = 0.f; acc[i][j][2] = 0.f; acc[i][j][3] = 0.f;
    }

#pragma unroll
  for (int pass = 0; pass < 2; ++pass) {
    const ushort* A = pass ? A2 : A1;
    const ushort* B = pass ? B2 : B1;
    const int K = pass ? K2 : K1;
    if (K == 0) continue;
    for (int k0 = 0; k0 < K; k0 += 64) {
#pragma unroll
      for (int it = 0; it < 4; ++it) {
        int o = so + it * 4096;
        int row = o >> 7;
        int colb = o & 127;
        int gcolb = colb ^ ((row & 7) << 4);
        const ushort* ga = A + (size_t)(m0 + row) * K + k0 + (gcolb >> 1);
        GLD16(ga, (char*)lsAB[0] + o);
        const ushort* gb = B + (size_t)(n0 + row) * K + k0 + (gcolb >> 1);
        GLD16(gb, (char*)lsAB[1] + o);
      }
      __syncthreads();
#pragma unroll
      for (int kk = 0; kk < 2; ++kk) {
        const int cb = ((kk * 64 + lg * 16) ^ fragswz) >> 1;
        s16x8 af[4], bfr[4];
#pragma unroll
        for (int i = 0; i < 4; ++i)
          af[i] = *(const s16x8*)&lsAB[0][(wr * 64 + i * 16 + l15) * 64 + cb];
#pragma unroll
        for (int j = 0; j < 4; ++j)
          bfr[j] = *(const s16x8*)&lsAB[1][(wc * 64 + j * 16 + l15) * 64 + cb];
#pragma unroll
        for (int i = 0; i < 4; ++i)
#pragma unroll
          for (int j = 0; j < 4; ++j)
            acc[i][j] = __builtin_amdgcn_mfma_f32_16x16x32_bf16(af[i], bfr[j], acc[i][j], 0, 0, 0);
      }
      __syncthreads();
    }
  }

  ushort* tile = (ushort*)lsAB;
#pragma unroll
  for (int j = 0; j < 4; ++j) {
    int col = wc * 64 + j * 16 + l15;
    float bv = bias ? b2f(bias[n0 + col]) : 0.f;
#pragma unroll
    for (int i = 0; i < 4; ++i) {
#pragma unroll
      for (int r = 0; r < 4; ++r) {
        int row = wr * 64 + i * 16 + lg * 4 + r;
        float v = acc[i][j][r] + bv;
        if (do_relu) v = fmaxf(v, 0.f);
        tile[row * 128 + (col ^ ((row & 7) << 3))] = f2b(v);
      }
    }
  }
  __syncthreads();
#pragma unroll
  for (int t = 0; t < 8; ++t) {
    int id = t * 256 + tid;
    int row = id >> 4;
    int c8 = id & 15;
    u16x8 v = *(const u16x8*)&tile[row * 128 + (c8 ^ (row & 7)) * 8];
    *(u16x8*)&C[(size_t)(m0 + row) * N + n0 + c8 * 8] = v;
  }
}

// ---------------- fused h2-GEMM + final linear -> dual-dtype h output ----------------
__global__ __launch_bounds__(256, 2)
void gemm_h2_final(const ushort* __restrict__ A1, const ushort* __restrict__ B1,
                   const ushort* __restrict__ A2, const ushort* __restrict__ B2,
                   const ushort* __restrict__ bias2, const ushort* __restrict__ Wlin,
                   const ushort* __restrict__ biasf,
                   ushort* __restrict__ CB, float* __restrict__ CF,
                   const int* __restrict__ flag, int K1, int K2) {
  __shared__ __align__(16) ushort lsAB[2][128 * 64];
  __shared__ __align__(16) ushort lsW[128 * 128];
  const int tid = threadIdx.x;
  const int lane = tid & 63;
  const int wid = tid >> 6;
  const int wr = wid >> 1, wc = wid & 1;
  const int m0 = blockIdx.x * 128;
  const int l15 = lane & 15;
  const int lg = lane >> 4;
  const int so = tid * 16;
  const int fragswz = (l15 & 7) << 4;
  const int fl = *flag;

#pragma unroll
  for (int it = 0; it < 8; ++it) {
    int o = so + it * 4096;
    int row = o >> 8;
    int colb = o & 255;
    int gcolb = colb ^ ((row & 7) << 4);
    GLD16(Wlin + (size_t)row * 128 + (gcolb >> 1), (char*)lsW + o);
  }

  f32x4 acc[4][4];
#pragma unroll
  for (int i = 0; i < 4; ++i)
#pragma unroll
    for (int j = 0; j < 4; ++j) {
      acc[i][j][0] = 0.f; acc[i][j][1] = 0.f; acc[i][j][2] = 0.f; acc[i][j][3] = 0.f;
    }

#pragma unroll
  for (int pass = 0; pass < 2; ++pass) {
    const ushort* A = pass ? A2 : A1;
    const ushort* B = pass ? B2 : B1;
    const int K = pass ? K2 : K1;
    for (int k0 = 0; k0 < K; k0 += 64) {
#pragma unroll
      for (int it = 0; it < 4; ++it) {
        int o = so + it * 4096;
        int row = o >> 7;
        int colb = o & 127;
        int gcolb = colb ^ ((row & 7) << 4);
        GLD16(A + (size_t)(m0 + row) * K + k0 + (gcolb >> 1), (char*)lsAB[0] + o);
        GLD16(B + (size_t)row * K + k0 + (gcolb >> 1), (char*)lsAB[1] + o);
      }
      __syncthreads();
#pragma unroll
      for (int kk = 0; kk < 2; ++kk) {
        const int cb = ((kk * 64 + lg * 16) ^ fragswz) >> 1;
        s16x8 af[4], bfr[4];
#pragma unroll
        for (int i = 0; i < 4; ++i)
          af[i] = *(const s16x8*)&lsAB[0][(wr * 64 + i * 16 + l15) * 64 + cb];
#pragma unroll
        for (int j = 0; j < 4; ++j)
          bfr[j] = *(const s16x8*)&lsAB[1][(wc * 64 + j * 16 + l15) * 64 + cb];
#pragma unroll
        for (int i = 0; i < 4; ++i)
#pragma unroll
          for (int j = 0; j < 4; ++j)
            acc[i][j] = __builtin_amdgcn_mfma_f32_16x16x32_bf16(af[i], bfr[j], acc[i][j], 0, 0, 0);
      }
      __syncthreads();
    }
  }

  ushort* tile = (ushort*)lsAB;
#pragma unroll
  for (int j = 0; j < 4; ++j) {
    int col = wc * 64 + j * 16 + l15;
    float bv = b2f(bias2[col]);
#pragma unroll
    for (int i = 0; i < 4; ++i) {
#pragma unroll
      for (int r = 0; r < 4; ++r) {
        int row = wr * 64 + i * 16 + lg * 4 + r;
        float v = fmaxf(acc[i][j][r] + bv, 0.f);
        tile[row * 128 + (col ^ ((row & 7) << 3))] = f2b(v);
      }
    }
  }
  __syncthreads();

  f32x4 acc2[4][4];
#pragma unroll
  for (int i = 0; i < 4; ++i)
#pragma unroll
    for (int j = 0; j < 4; ++j) {
      acc2[i][j][0] = 0.f; acc2[i][j][1] = 0.f; acc2[i][j][2] = 0.f; acc2[i][j][3] = 0.f;
    }
#pragma unroll
  for (int kk = 0; kk < 4; ++kk) {
    s16x8 af[4], bfr[4];
#pragma unroll
    for (int i = 0; i < 4; ++i) {
      int row = wr * 64 + i * 16 + l15;
      int cb = (kk * 32 + lg * 8) ^ ((row & 7) << 3);
      af[i] = *(const s16x8*)&tile[row * 128 + cb];
    }
#pragma unroll
    for (int j = 0; j < 4; ++j) {
      int row = wc * 64 + j * 16 + l15;
      int cb = (kk * 32 + lg * 8) ^ ((row & 7) << 3);
      bfr[j] = *(const s16x8*)&lsW[row * 128 + cb];
    }
#pragma unroll
    for (int i = 0; i < 4; ++i)
#pragma unroll
      for (int j = 0; j < 4; ++j)
        acc2[i][j] = __builtin_amdgcn_mfma_f32_16x16x32_bf16(af[i], bfr[j], acc2[i][j], 0, 0, 0);
  }
  __syncthreads();

#pragma unroll
  for (int j = 0; j < 4; ++j) {
    int col = wc * 64 + j * 16 + l15;
    float bv = b2f(biasf[col]);
#pragma unroll
    for (int i = 0; i < 4; ++i) {
#pragma unroll
      for (int r = 0; r < 4; ++r) {
        int row = wr * 64 + i * 16 + lg * 4 + r;
        tile[row * 128 + (col ^ ((row & 7) << 3))] = f2b(acc2[i][j][r] + bv);
      }
    }
  }
  __syncthreads();
#pragma unroll
  for (int t = 0; t < 8; ++t) {
    int id = t * 256 + tid;
    int row = id >> 4;
    int c8 = id & 15;
    u16x8 v = *(const u16x8*)&tile[row * 128 + (c8 ^ (row & 7)) * 8];
    size_t off = (size_t)(m0 + row) * 128 + c8 * 8;
    if (fl) {
      float4 f0, f1;
      f0.x = b2f(v[0]); f0.y = b2f(v[1]); f0.z = b2f(v[2]); f0.w = b2f(v[3]);
      f1.x = b2f(v[4]); f1.y = b2f(v[5]); f1.z = b2f(v[6]); f1.w = b2f(v[7]);
      *(float4*)&CF[off] = f0;
      *(float4*)&CF[off + 4] = f1;
    } else {
      *(u16x8*)&CB[off] = v;
    }
  }
}

// ---------------- kriging gather ----------------
__global__ void gather_out(const ushort* __restrict__ hb, const float* __restrict__ hf,
                           const int* __restrict__ map_id, void* __restrict__ dout,
                           const int* __restrict__ flag,
                           int K, int num_nodes, int total, int N) {
  int i = blockIdx.x * 256 + threadIdx.x;
  if (i >= total) return;
  int f = i & 127;
  int row = i >> 7;
  int b = row / K;
  unsigned node = (unsigned)(b * num_nodes + map_id[row]);
  bool ok = node < (unsigned)N;
  if (*flag) {
    ((float*)dout)[i] = ok ? hf[(size_t)node * 128 + f] : 0.f;
  } else {
    ((ushort*)dout)[i] = ok ? hb[(size_t)node * 128 + f] : (ushort)0;
  }
}

extern "C" void kernel_launch(void* const* d_in, const int* in_sizes, int n_in,
                              void* d_out, int out_size, void* d_ws, size_t ws_size,
                              hipStream_t stream) {
  const void* x    = d_in[0];
  const int*  ei   = (const int*)d_in[1];
  const int*  mapi = (const int*)d_in[2];
  const void* Wp1  = d_in[4];
  const void* bp1  = d_in[5];
  const void* Wl1  = d_in[6];
  const void* bl1  = d_in[7];
  const void* Wr1  = d_in[8];
  const void* Wp2  = d_in[9];
  const void* bp2  = d_in[10];
  const void* Wl2  = d_in[11];
  const void* bl2  = d_in[12];
  const void* Wr2  = d_in[13];
  const void* Wlin = d_in[14];
  const void* blin = d_in[15];

  const int NN = in_sizes[0] / 256;   // 80000
  const int E  = in_sizes[1] / 2;     // 1.28M
  const int MAPROWS = in_sizes[2];    // 40000
  const int BS = 16;
  const int NUM_NODES = NN / BS;      // 5000
  const int KMAP = MAPROWS / BS;      // 2500
  const int NBUCK = (NN + 511) >> 9;  // 157
  const int* src = ei;
  const int* dst = ei + E;

  ushort* houtB = (ushort*)d_out + (size_t)MAPROWS * 128;
  float*  houtF = (float*)d_out + (size_t)MAPROWS * 128;
  int2* pairs = (int2*)((char*)d_out + (size_t)MAPROWS * 128 * 4);

  char* sc = (char*)d_out;
  auto carve_sc = [&](size_t bytes) {
    char* p = sc; sc += (bytes + 255) & ~(size_t)255; return p;
  };
  ushort* Wp1T  = (ushort*)carve_sc(256 * 256 * 2);
  ushort* Wl1T  = (ushort*)carve_sc(256 * 256 * 2);
  ushort* Wr1T  = (ushort*)carve_sc(256 * 256 * 2);
  ushort* Wp2T  = (ushort*)carve_sc(256 * 256 * 2);
  ushort* Wl2T  = (ushort*)carve_sc(128 * 256 * 2);
  ushort* Wr2T  = (ushort*)carve_sc(128 * 256 * 2);
  ushort* WlinT = (ushort*)carve_sc(128 * 128 * 2);
  ushort* bp1c  = (ushort*)carve_sc(256 * 2);
  ushort* bl1c  = (ushort*)carve_sc(256 * 2);
  ushort* bp2c  = (ushort*)carve_sc(256 * 2);
  ushort* bl2c  = (ushort*)carve_sc(128 * 2);
  ushort* blinc = (ushort*)carve_sc(128 * 2);
  int* rowptr = (int*)carve_sc(((size_t)NN + 1) * 4);
  int* eidx   = (int*)carve_sc((size_t)E * 4);
  int* bcnt   = (int*)carve_sc(2048);
  int* bscan  = (int*)carve_sc(2048 + 4);
  int* bpos   = (int*)carve_sc(2048);

  char* w = (char*)d_ws;
  auto carve = [&](size_t bytes) {
    char* p = w; w += (bytes + 255) & ~(size_t)255; return p;
  };
  int*    flag = (int*)carve(256);
  ushort* xb   = (ushort*)carve((size_t)NN * 256 * 2);  // x_bf16 -> mean2
  ushort* bA   = (ushort*)carve((size_t)NN * 256 * 2);  // xp1 -> h1
  ushort* bB   = (ushort*)carve((size_t)NN * 256 * 2);  // mean1 -> xp2

  // --- dtype detect + conversions ---
  detect_dtype<<<dim3(1), 256, 0, stream>>>((const ushort*)x, flag);
  convert_x<<<dim3((NN * 256 / 8 + 255) / 256), 256, 0, stream>>>(x, xb, flag, NN * 256);

  WPack wp;
  wp.d[0] = {Wp1, Wp1T, 256, 256};
  wp.d[1] = {Wl1, Wl1T, 256, 256};
  wp.d[2] = {Wr1, Wr1T, 256, 256};
  wp.d[3] = {Wp2, Wp2T, 256, 256};
  wp.d[4] = {Wl2, Wl2T, 256, 128};
  wp.d[5] = {Wr2, Wr2T, 256, 128};
  wp.d[6] = {Wlin, WlinT, 128, 128};
  transpose_convert_all<<<dim3(256, 7), 256, 0, stream>>>(wp, flag);

  BPack bp;
  bp.d[0] = {bp1, bp1c, 256, 1};
  bp.d[1] = {bl1, bl1c, 256, 1};
  bp.d[2] = {bp2, bp2c, 256, 1};
  bp.d[3] = {bl2, bl2c, 128, 1};
  bp.d[4] = {blin, blinc, 128, 1};
  convert_vec_all<<<dim3(1, 5), 256, 0, stream>>>(bp, flag);

  // --- CSR build (two-level counting sort, LDS-finalized) ---
  hipMemsetAsync(bcnt, 0, 2048, stream);
  hist_bucket_kernel<<<dim3((E + 2047) / 2048), 256, 0, stream>>>(dst, bcnt, E, NN, NBUCK);
  scan_buckets<<<dim3(1), 256, 0, stream>>>(bcnt, bscan, bpos, rowptr, NBUCK, NN);
  bin_scatter<<<dim3((E + 4095) / 4096), 256, 0, stream>>>(src, dst, bpos, pairs, E, NN, NBUCK);
  bucket_finalize<<<dim3(NBUCK), 256, 0, stream>>>(pairs, bscan, rowptr, eidx, NN);

  dim3 blk(256);
  dim3 g256(NN / 128, 2);   // N=256
  dim3 gagg((NN + 3) / 4);

  // --- layer 1 ---
  gemm_bf16<<<g256, blk, 0, stream>>>(xb, Wp1T, nullptr, nullptr, bp1c, bA,
                                      NN, 256, 256, 0, 1);                          // xp1
  agg_mean_v3<<<gagg, blk, 0, stream>>>(bA, rowptr, eidx, bB, NN);                  // mean1
  gemm_bf16<<<g256, blk, 0, stream>>>(bB, Wl1T, xb, Wr1T, bl1c, bA,
                                      NN, 256, 256, 256, 1);                        // h1

  // --- layer 2 ---
  gemm_bf16<<<g256, blk, 0, stream>>>(bA, Wp2T, nullptr, nullptr, bp2c, bB,
                                      NN, 256, 256, 0, 1);                          // xp2
  agg_mean_v3<<<gagg, blk, 0, stream>>>(bB, rowptr, eidx, xb, NN);                  // mean2

  // --- fused h2 + final linear -> dual-dtype h in d_out ---
  gemm_h2_final<<<dim3(NN / 128), blk, 0, stream>>>(xb, Wl2T, bA, Wr2T, bl2c,
                                                    WlinT, blinc, houtB, houtF,
                                                    flag, 256, 256);

  // --- kriging gather ---
  int total = MAPROWS * 128;
  gather_out<<<dim3((total + 255) / 256), 256, 0, stream>>>(houtB, houtF, mapi, d_out,
                                                            flag, KMAP, NUM_NODES, total, NN);
}